// Round 12
// baseline (1124.014 us; speedup 1.0000x reference)
//
#include <hip/hip_runtime.h>
#include <math.h>

#define BB   2
#define SS   2048
#define HIDD 1024
#define ROWS 4096
#define NCH  32      // 64-row chunks (prep level)
#define CH   64
#define NMC  16      // 128-row macro-chunks (scan level)

typedef unsigned short u16t;
typedef unsigned int   u32t;

typedef __attribute__((ext_vector_type(8))) short bf16x8;
typedef __attribute__((ext_vector_type(4))) float f32x4;

__device__ __forceinline__ float bf2f(u16t u) { return __uint_as_float(((u32t)u) << 16); }
__device__ __forceinline__ u16t f2bf(float f) {
    u32t b = __float_as_uint(f);
    return (u16t)((b + 0x7FFFu + ((b >> 16) & 1u)) >> 16);
}
__device__ __forceinline__ float lo_bf(u32t u) { return __uint_as_float(u << 16); }
__device__ __forceinline__ float hi_bf(u32t u) { return __uint_as_float(u & 0xFFFF0000u); }

__device__ __forceinline__ float waveReduceSum(float v) {
#pragma unroll
    for (int m = 1; m < 64; m <<= 1) v += __shfl_xor(v, m, 64);
    return v;
}

__device__ __forceinline__ void gload16(const void* g, void* l) {
    __builtin_amdgcn_global_load_lds(
        (const __attribute__((address_space(1))) unsigned int*)g,
        (__attribute__((address_space(3))) unsigned int*)l, 16, 0, 0);
}

#define MFMA(a, b, c) __builtin_amdgcn_mfma_f32_16x16x32_bf16(a, b, c, 0, 0, 0)

// =================== X f32 -> bf16 ======================================
__global__ __launch_bounds__(256) void f2bf_kernel(const float* __restrict__ in,
                                                   u16t* __restrict__ out) {
    const size_t idx = ((size_t)blockIdx.x * 256 + threadIdx.x) * 8;
    float4 a = *(const float4*)&in[idx];
    float4 b = *(const float4*)&in[idx + 4];
    ushort4 o1, o2;
    o1.x = f2bf(a.x); o1.y = f2bf(a.y); o1.z = f2bf(a.z); o1.w = f2bf(a.w);
    o2.x = f2bf(b.x); o2.y = f2bf(b.y); o2.z = f2bf(b.z); o2.w = f2bf(b.w);
    *(ushort4*)&out[idx] = o1;
    *(ushort4*)&out[idx + 4] = o2;
}

// ====== 4 weight transposes fused in one launch (blockIdx.z selects) ======
__global__ __launch_bounds__(256) void transpose_w4(const float* __restrict__ W0,
                                                    const float* __restrict__ W1,
                                                    const float* __restrict__ W2,
                                                    const float* __restrict__ W3,
                                                    u16t* __restrict__ T0,
                                                    u16t* __restrict__ T1,
                                                    u16t* __restrict__ T2,
                                                    u16t* __restrict__ T3) {
    __shared__ u16t tile[64][65];
    const int z = blockIdx.z;
    const float* W = (z == 0) ? W0 : (z == 1) ? W1 : (z == 2) ? W2 : W3;
    u16t* WT = (z == 0) ? T0 : (z == 1) ? T1 : (z == 2) ? T2 : T3;
    const int t = threadIdx.x;
    const int r0 = blockIdx.y * 64, c0 = blockIdx.x * 64;
    const int lr = t >> 2, lc4 = (t & 3) * 16;
#pragma unroll
    for (int m = 0; m < 4; ++m) {
        float4 v = *(const float4*)&W[(size_t)(r0 + lr) * 1024 + c0 + lc4 + m * 4];
        tile[lr][lc4 + m * 4 + 0] = f2bf(v.x);
        tile[lr][lc4 + m * 4 + 1] = f2bf(v.y);
        tile[lr][lc4 + m * 4 + 2] = f2bf(v.z);
        tile[lr][lc4 + m * 4 + 3] = f2bf(v.w);
    }
    __syncthreads();
#pragma unroll
    for (int m = 0; m < 16; ++m)
        WT[(size_t)(c0 + lr) * 1024 + r0 + lc4 + m] = tile[lc4 + m][lr];
}

// ======= MFMA GEMM: C[M,N] = A[M,K] * BT[N,K]^T, plane-strided B/C =======
__global__ __launch_bounds__(256) void gemm_mfma(const u16t* __restrict__ A,
                                                 const u16t* __restrict__ BT,
                                                 float* __restrict__ Cf,
                                                 u16t* __restrict__ Cb, int obf,
                                                 int M, int N, int K,
                                                 size_t bStrideP, size_t cStrideP,
                                                 int CX) {
    __shared__ u16t As[128 * 64];
    __shared__ u16t Bs[128 * 64];
    const int t = threadIdx.x, l = t & 63, w = t >> 6;
    const int wr = w >> 1, wc = w & 1;

    const int lin = blockIdx.y * gridDim.x + blockIdx.x;
    const int xcd = lin & 7, idx = lin >> 3;
    const int Wc = gridDim.x / CX;
    const int Hc = (gridDim.y * CX) >> 3;
    const int colB = (xcd % CX) * Wc + idx % Wc;
    const int rowB = (xcd / CX) * Hc + idx / Wc;

    const int rowBase = rowB * 128, colBase = colB * 128;
    const int l15 = l & 15, g4 = l >> 4;

    const int bplane = colBase >> 10;
    const int bcol = colBase & 1023;

    const int srow = l >> 3;
    const int sj = (l & 7) ^ srow;
    const u16t* aSrc = A + (size_t)(rowBase + srow) * K + sj * 8;
    const u16t* bSrc = BT + (size_t)bplane * bStrideP + (size_t)(bcol + srow) * K + sj * 8;

    f32x4 acc[4][4];
#pragma unroll
    for (int i = 0; i < 4; ++i)
#pragma unroll
        for (int j = 0; j < 4; ++j) acc[i][j] = (f32x4){0.f, 0.f, 0.f, 0.f};

    for (int k0 = 0; k0 < K; k0 += 64) {
#pragma unroll
        for (int i = 0; i < 4; ++i) {
            const int rb = (i * 4 + w) * 8;
            gload16(aSrc + (size_t)rb * K + k0, &As[rb * 64]);
            gload16(bSrc + (size_t)rb * K + k0, &Bs[rb * 64]);
        }
        __syncthreads();
#pragma unroll
        for (int kh = 0; kh < 2; ++kh) {
            bf16x8 aF[4], bF[4];
#pragma unroll
            for (int mi = 0; mi < 4; ++mi) {
                const int row = wr * 64 + mi * 16 + l15;
                const int phys = (kh * 4 + g4) ^ (row & 7);
                aF[mi] = *(const bf16x8*)&As[row * 64 + phys * 8];
            }
#pragma unroll
            for (int ni = 0; ni < 4; ++ni) {
                const int row = wc * 64 + ni * 16 + l15;
                const int phys = (kh * 4 + g4) ^ (row & 7);
                bF[ni] = *(const bf16x8*)&Bs[row * 64 + phys * 8];
            }
#pragma unroll
            for (int mi = 0; mi < 4; ++mi)
#pragma unroll
                for (int ni = 0; ni < 4; ++ni)
                    acc[mi][ni] = MFMA(aF[mi], bF[ni], acc[mi][ni]);
        }
        __syncthreads();
    }
#pragma unroll
    for (int mi = 0; mi < 4; ++mi)
#pragma unroll
        for (int ni = 0; ni < 4; ++ni)
#pragma unroll
            for (int rg = 0; rg < 4; ++rg) {
                const int row = rowBase + wr * 64 + mi * 16 + g4 * 4 + rg;
                const int col = colBase + wc * 64 + ni * 16 + l15;
                const int plane = col >> 10, cc = col & 1023;
                const float v = acc[mi][ni][rg];
                if (obf) Cb[(size_t)plane * cStrideP + (size_t)row * 1024 + cc] = f2bf(v);
                else     Cf[(size_t)plane * cStrideP + (size_t)row * 1024 + cc] = v;
            }
}

// =================== beta = sigmoid(X @ Wb) ==============================
__global__ __launch_bounds__(256) void beta_kernel(const float* __restrict__ X,
                                                   const float* __restrict__ Wb,
                                                   float* __restrict__ beta) {
    const int gw   = (blockIdx.x * blockDim.x + threadIdx.x) >> 6;
    const int lane = threadIdx.x & 63;
    if (gw >= ROWS) return;
    const float* x = X + (size_t)gw * HIDD;
    float a0 = 0.f, a1 = 0.f, a2 = 0.f, a3 = 0.f;
#pragma unroll
    for (int i = 0; i < 4; ++i) {
        const int k = lane * 16 + i * 4;
        float4 xv = *(const float4*)&x[k];
        float4 w0 = *(const float4*)&Wb[(size_t)(k + 0) * 4];
        float4 w1 = *(const float4*)&Wb[(size_t)(k + 1) * 4];
        float4 w2 = *(const float4*)&Wb[(size_t)(k + 2) * 4];
        float4 w3 = *(const float4*)&Wb[(size_t)(k + 3) * 4];
        a0 += xv.x * w0.x + xv.y * w1.x + xv.z * w2.x + xv.w * w3.x;
        a1 += xv.x * w0.y + xv.y * w1.y + xv.z * w2.y + xv.w * w3.y;
        a2 += xv.x * w0.z + xv.y * w1.z + xv.z * w2.z + xv.w * w3.z;
        a3 += xv.x * w0.w + xv.y * w1.w + xv.z * w2.w + xv.w * w3.w;
    }
    a0 = waveReduceSum(a0); a1 = waveReduceSum(a1);
    a2 = waveReduceSum(a2); a3 = waveReduceSum(a3);
    if (lane == 0) {
        float4 o = make_float4(1.f / (1.f + expf(-a0)), 1.f / (1.f + expf(-a1)),
                               1.f / (1.f + expf(-a2)), 1.f / (1.f + expf(-a3)));
        *(float4*)&beta[(size_t)gw * 4] = o;
    }
}

// == causal conv(K=4)+silu(+l2norm), q & v fused in one launch (blockIdx.y) ==
__global__ __launch_bounds__(256) void conv_qv(const u16t* __restrict__ inQ,
                                               const float* __restrict__ wQ,
                                               u16t* __restrict__ outQ,
                                               const u16t* __restrict__ inV,
                                               const float* __restrict__ wV,
                                               u16t* __restrict__ outV) {
    const int isQ = (blockIdx.y == 0);
    const u16t* in = isQ ? inQ : inV;
    const float* w = isQ ? wQ : wV;
    u16t* out      = isQ ? outQ : outV;
    const int doL2 = isQ;

    const int gw   = (blockIdx.x * blockDim.x + threadIdx.x) >> 6;
    const int lane = threadIdx.x & 63;
    const int r = gw >> 2;
    const int h = gw & 3;
    const int b = r >> 11;
    const int s = r & 2047;
    const int c4 = h * 256 + lane * 4;

    const float4 wr0 = *(const float4*)&w[(size_t)(c4 + 0) * 4];
    const float4 wr1 = *(const float4*)&w[(size_t)(c4 + 1) * 4];
    const float4 wr2 = *(const float4*)&w[(size_t)(c4 + 2) * 4];
    const float4 wr3 = *(const float4*)&w[(size_t)(c4 + 3) * 4];

    const size_t rowB = (size_t)(b << 11);
    float x0[4] = {0, 0, 0, 0}, x1[4] = {0, 0, 0, 0}, x2[4] = {0, 0, 0, 0}, x3[4];
    ushort4 u;
    if (s >= 3) { u = *(const ushort4*)&in[(rowB + s - 3) * HIDD + c4];
        x0[0] = bf2f(u.x); x0[1] = bf2f(u.y); x0[2] = bf2f(u.z); x0[3] = bf2f(u.w); }
    if (s >= 2) { u = *(const ushort4*)&in[(rowB + s - 2) * HIDD + c4];
        x1[0] = bf2f(u.x); x1[1] = bf2f(u.y); x1[2] = bf2f(u.z); x1[3] = bf2f(u.w); }
    if (s >= 1) { u = *(const ushort4*)&in[(rowB + s - 1) * HIDD + c4];
        x2[0] = bf2f(u.x); x2[1] = bf2f(u.y); x2[2] = bf2f(u.z); x2[3] = bf2f(u.w); }
    u = *(const ushort4*)&in[(rowB + s) * HIDD + c4];
    x3[0] = bf2f(u.x); x3[1] = bf2f(u.y); x3[2] = bf2f(u.z); x3[3] = bf2f(u.w);

    float y0 = wr0.x * x0[0] + wr0.y * x1[0] + wr0.z * x2[0] + wr0.w * x3[0];
    float y1 = wr1.x * x0[1] + wr1.y * x1[1] + wr1.z * x2[1] + wr1.w * x3[1];
    float y2 = wr2.x * x0[2] + wr2.y * x1[2] + wr2.z * x2[2] + wr2.w * x3[2];
    float y3 = wr3.x * x0[3] + wr3.y * x1[3] + wr3.z * x2[3] + wr3.w * x3[3];

    y0 = y0 / (1.f + expf(-y0)); y1 = y1 / (1.f + expf(-y1));
    y2 = y2 / (1.f + expf(-y2)); y3 = y3 / (1.f + expf(-y3));

    if (doL2) {
        float ss = y0 * y0 + y1 * y1 + y2 * y2 + y3 * y3;
        ss = waveReduceSum(ss);
        float sc = rsqrtf(ss + 1e-6f);
        y0 *= sc; y1 *= sc; y2 *= sc; y3 *= sc;
    }
    ushort4 o;
    o.x = f2bf(y0); o.y = f2bf(y1); o.z = f2bf(y2); o.w = f2bf(y3);
    *(ushort4*)&out[(size_t)r * HIDD + c4] = o;
}

// ====== conv for K: row-major out + transposed ktr[bh*256+r][t] ==========
__global__ __launch_bounds__(256) void conv_k_chunk(const u16t* __restrict__ pre,
                                                    const float* __restrict__ w,
                                                    u16t* __restrict__ rowout,
                                                    u16t* __restrict__ trout) {
    const int t = threadIdx.x;
    const int bh = blockIdx.x >> 5, c = blockIdx.x & 31;
    const int b = bh >> 2, h = bh & 3;
    const int i = t >> 2, g = t & 3;
    const int s = c * 64 + i;
    const size_t row = (size_t)b * 2048 + s;
    const int ch0 = h * 256 + g * 64;
    const int cloc = g * 64;
    float y[64];
#pragma unroll
    for (int m = 0; m < 8; ++m) {
        const int cm = ch0 + m * 8;
        uint4 x3 = *(const uint4*)&pre[row * 1024 + cm];
        uint4 x2 = (s >= 1) ? *(const uint4*)&pre[(row - 1) * 1024 + cm] : make_uint4(0, 0, 0, 0);
        uint4 x1 = (s >= 2) ? *(const uint4*)&pre[(row - 2) * 1024 + cm] : make_uint4(0, 0, 0, 0);
        uint4 x0 = (s >= 3) ? *(const uint4*)&pre[(row - 3) * 1024 + cm] : make_uint4(0, 0, 0, 0);
        u32t c0[4] = {x0.x, x0.y, x0.z, x0.w};
        u32t c1[4] = {x1.x, x1.y, x1.z, x1.w};
        u32t c2[4] = {x2.x, x2.y, x2.z, x2.w};
        u32t c3[4] = {x3.x, x3.y, x3.z, x3.w};
#pragma unroll
        for (int p = 0; p < 4; ++p) {
            const int ch = m * 8 + p * 2;
            float4 wA = *(const float4*)&w[(size_t)(ch0 + ch) * 4];
            float4 wB = *(const float4*)&w[(size_t)(ch0 + ch + 1) * 4];
            float ya = wA.x * lo_bf(c0[p]) + wA.y * lo_bf(c1[p]) + wA.z * lo_bf(c2[p]) + wA.w * lo_bf(c3[p]);
            float yb = wB.x * hi_bf(c0[p]) + wB.y * hi_bf(c1[p]) + wB.z * hi_bf(c2[p]) + wB.w * hi_bf(c3[p]);
            ya = ya / (1.f + expf(-ya));
            yb = yb / (1.f + expf(-yb));
            y[ch] = ya; y[ch + 1] = yb;
        }
    }
    float ss = 0.f;
#pragma unroll
    for (int e = 0; e < 64; ++e) ss += y[e] * y[e];
    ss += __shfl_xor(ss, 1);
    ss += __shfl_xor(ss, 2);
    const float sc = rsqrtf(ss + 1e-6f);
#pragma unroll
    for (int m = 0; m < 8; ++m) {
        uint4 o;
        u32t* op = (u32t*)&o;
#pragma unroll
        for (int p = 0; p < 4; ++p) {
            u16t a = f2bf(y[m * 8 + p * 2] * sc);
            u16t bb2 = f2bf(y[m * 8 + p * 2 + 1] * sc);
            op[p] = (u32t)a | ((u32t)bb2 << 16);
        }
        *(uint4*)&rowout[row * 1024 + ch0 + m * 8] = o;
    }
#pragma unroll
    for (int e = 0; e < 64; ++e)
        trout[((size_t)bh * 256 + cloc + e) * 2048 + s] = f2bf(y[e] * sc);
}

// ====== prep: per 64-chunk T=(I+strict_lower(diag(b)KK^T))^-1 (hi/lo) =====
__global__ __launch_bounds__(256) void prep_kernel(const u16t* __restrict__ qcb,
                                                   const u16t* __restrict__ kcb,
                                                   const float* __restrict__ beta,
                                                   u16t* __restrict__ Tghi,
                                                   u16t* __restrict__ Tglo,
                                                   u16t* __restrict__ Agb) {
    __shared__ float KT[256][68];
    __shared__ float QT[256][68];
    __shared__ float Af[64][68];
    const int t = threadIdx.x;
    const int bhc = blockIdx.x;
    const int bh = bhc >> 5, c = bhc & 31;
    const int b = bh >> 2, h = bh & 3;
    const int tb = b * SS + c * CH;

    {
        const int i = t & 63, rb = t >> 6;
        const u16t* kg = kcb + (size_t)(tb + i) * HIDD + h * 256 + rb * 64;
        const u16t* qg = qcb + (size_t)(tb + i) * HIDD + h * 256 + rb * 64;
#pragma unroll
        for (int m = 0; m < 8; ++m) {
            uint4 kv = ((const uint4*)kg)[m];
            uint4 qv = ((const uint4*)qg)[m];
            u32t kw[4] = {kv.x, kv.y, kv.z, kv.w};
            u32t qw[4] = {qv.x, qv.y, qv.z, qv.w};
#pragma unroll
            for (int n = 0; n < 4; ++n) {
                int rr = rb * 64 + m * 8 + n * 2;
                KT[rr][i]     = lo_bf(kw[n]);
                KT[rr + 1][i] = hi_bf(kw[n]);
                QT[rr][i]     = lo_bf(qw[n]);
                QT[rr + 1][i] = hi_bf(qw[n]);
            }
        }
    }
    __syncthreads();

    const int it = t & 63, jb = t >> 6;
    float kk[16], qk[16];
#pragma unroll
    for (int m = 0; m < 16; ++m) { kk[m] = 0.f; qk[m] = 0.f; }
#pragma unroll 2
    for (int r = 0; r < 256; ++r) {
        float ki = KT[r][it];
        float qi = QT[r][it];
        float4 ka = *(const float4*)&KT[r][jb * 16 + 0];
        float4 kb = *(const float4*)&KT[r][jb * 16 + 4];
        float4 kc = *(const float4*)&KT[r][jb * 16 + 8];
        float4 kd = *(const float4*)&KT[r][jb * 16 + 12];
        float kj[16] = {ka.x, ka.y, ka.z, ka.w, kb.x, kb.y, kb.z, kb.w,
                        kc.x, kc.y, kc.z, kc.w, kd.x, kd.y, kd.z, kd.w};
#pragma unroll
        for (int m = 0; m < 16; ++m) { kk[m] += ki * kj[m]; qk[m] += qi * kj[m]; }
    }

    const float bta = beta[(size_t)(tb + it) * 4 + h];
    u16t* ag = Agb + (size_t)bhc * 4096 + (size_t)it * 64 + jb * 16;
#pragma unroll
    for (int m = 0; m < 16; ++m) {
        int j = jb * 16 + m;
        Af[it][j] = (j < it) ? bta * kk[m] : 0.f;
    }
#pragma unroll
    for (int m4 = 0; m4 < 4; ++m4) {
        ushort4 o;
        o.x = f2bf((jb * 16 + m4 * 4 + 0 <= it) ? qk[m4 * 4 + 0] : 0.f);
        o.y = f2bf((jb * 16 + m4 * 4 + 1 <= it) ? qk[m4 * 4 + 1] : 0.f);
        o.z = f2bf((jb * 16 + m4 * 4 + 2 <= it) ? qk[m4 * 4 + 2] : 0.f);
        o.w = f2bf((jb * 16 + m4 * 4 + 3 <= it) ? qk[m4 * 4 + 3] : 0.f);
        *(ushort4*)&ag[m4 * 4] = o;
    }
    __syncthreads();

    if (t < 64) {
        const int ccol = t;
        float tc[64];
#pragma unroll
        for (int j = 0; j < 64; ++j) tc[j] = (j == ccol) ? 1.f : 0.f;
#pragma unroll
        for (int i = 1; i < 64; ++i) {
            float a = 0.f;
#pragma unroll
            for (int j = 0; j < i; ++j) a += Af[i][j] * tc[j];
            tc[i] -= a;
        }
        u16t* th = Tghi + (size_t)bhc * 4096;
        u16t* tl = Tglo + (size_t)bhc * 4096;
#pragma unroll
        for (int i = 0; i < 64; ++i) {
            u16t hi = f2bf(tc[i]);
            th[i * 64 + ccol] = hi;
            tl[i * 64 + ccol] = f2bf(tc[i] - bf2f(hi));
        }
    }
}

// ====== prep2: per 128-macro-chunk compose T21 = -T22*G21*T11, A21 ========
// block = (bh, mc): 128 blocks x 256 thr.
__global__ __launch_bounds__(256) void prep2_kernel(const u16t* __restrict__ qcb,
                                                    const u16t* __restrict__ kcb,
                                                    const float* __restrict__ beta,
                                                    const u16t* __restrict__ Tghi,
                                                    const u16t* __restrict__ Tglo,
                                                    u16t* __restrict__ T21hi,
                                                    u16t* __restrict__ T21lo,
                                                    u16t* __restrict__ A21g) {
    __shared__ float Gs[64][68];
    __shared__ float T11f[64][68];
    __shared__ float T22f[64][68];
    __shared__ float Pf[64][68];

    const int t = threadIdx.x, l = t & 63, w = t >> 6;
    const int bhmc = blockIdx.x;
    const int bh = bhmc >> 4, mc = bhmc & 15;
    const int b = bh >> 2, h = bh & 3;
    const int t1 = b * SS + mc * 128;
    const int t2 = t1 + 64;
    const int vlow = l & 15, g4 = l >> 4;

    // --- G21 = K2*K1^T, A21 = Q2*K1^T via MFMA; wave w = i-tile -----------
    bf16x8 k2f[8], q2f[8];
    {
        const size_t rb = (size_t)(t2 + 16 * w + vlow) * 1024 + h * 256 + g4 * 8;
#pragma unroll
        for (int ks = 0; ks < 8; ++ks) {
            k2f[ks] = *(const bf16x8*)(kcb + rb + ks * 32);
            q2f[ks] = *(const bf16x8*)(qcb + rb + ks * 32);
        }
    }
    float bta2[4];
#pragma unroll
    for (int rg = 0; rg < 4; ++rg)
        bta2[rg] = beta[(size_t)(t2 + 16 * w + 4 * g4 + rg) * 4 + h];

#pragma unroll
    for (int jt = 0; jt < 4; ++jt) {
        bf16x8 k1f[8];
        const size_t rb1 = (size_t)(t1 + 16 * jt + vlow) * 1024 + h * 256 + g4 * 8;
#pragma unroll
        for (int ks = 0; ks < 8; ++ks)
            k1f[ks] = *(const bf16x8*)(kcb + rb1 + ks * 32);
        f32x4 Gacc = (f32x4){0.f, 0.f, 0.f, 0.f};
        f32x4 Aacc = (f32x4){0.f, 0.f, 0.f, 0.f};
#pragma unroll
        for (int ks = 0; ks < 8; ++ks) {
            Gacc = MFMA(k2f[ks], k1f[ks], Gacc);
            Aacc = MFMA(q2f[ks], k1f[ks], Aacc);
        }
        const int j = 16 * jt + vlow;
#pragma unroll
        for (int rg = 0; rg < 4; ++rg) {
            const int i = 16 * w + 4 * g4 + rg;
            Gs[i][j] = bta2[rg] * Gacc[rg];
            A21g[(size_t)bhmc * 4096 + (size_t)i * 64 + j] = f2bf(Aacc[rg]);
        }
    }
    // --- stage T11, T22 (f32 = hi + lo) ------------------------------------
    {
        const size_t b11 = (size_t)(bh * 32 + 2 * mc) * 4096;
        const size_t b22 = (size_t)(bh * 32 + 2 * mc + 1) * 4096;
        for (int idx = t; idx < 4096; idx += 256) {
            const int i = idx >> 6, j = idx & 63;
            T11f[i][j] = bf2f(Tghi[b11 + idx]) + bf2f(Tglo[b11 + idx]);
            T22f[i][j] = bf2f(Tghi[b22 + idx]) + bf2f(Tglo[b22 + idx]);
        }
    }
    __syncthreads();

    // --- P = Gs * T11f -------------------------------------------------------
    {
        const int col = t & 63, rq = t >> 6;
        for (int ii = 0; ii < 16; ++ii) {
            const int i = rq * 16 + ii;
            float a = 0.f;
#pragma unroll 8
            for (int j = 0; j < 64; ++j) a += Gs[i][j] * T11f[j][col];
            Pf[i][col] = a;
        }
    }
    __syncthreads();

    // --- T21 = -T22f * Pf ----------------------------------------------------
    {
        const int col = t & 63, rq = t >> 6;
        for (int ii = 0; ii < 16; ++ii) {
            const int i = rq * 16 + ii;
            float a = 0.f;
#pragma unroll 8
            for (int j = 0; j < 64; ++j) a += T22f[i][j] * Pf[j][col];
            a = -a;
            const u16t hi = f2bf(a);
            T21hi[(size_t)bhmc * 4096 + (size_t)i * 64 + col] = hi;
            T21lo[(size_t)bhmc * 4096 + (size_t)i * 64 + col] = f2bf(a - bf2f(hi));
        }
    }
}

// ====== MFMA scan v9: 128-row macro-chunks, 8 waves (512 thr), 128 blocks ==
__global__ __launch_bounds__(512, 1) void scan_mfma(const u16t* __restrict__ qcb,
                                                    const u16t* __restrict__ kcb,
                                                    const u16t* __restrict__ ktr,
                                                    const u16t* __restrict__ vcb,
                                                    const float* __restrict__ beta,
                                                    const u16t* __restrict__ TghiG,
                                                    const u16t* __restrict__ TgloG,
                                                    const u16t* __restrict__ AgbG,
                                                    const u16t* __restrict__ T21hi,
                                                    const u16t* __restrict__ T21lo,
                                                    const u16t* __restrict__ A21g,
                                                    u16t* __restrict__ o_raw) {
    __shared__ u16t Shi[16 * 256];  // [v][r] slot-XOR swizzled (unchanged layout)
    __shared__ u16t Slo[16 * 256];
    __shared__ u16t Rhi[16 * 128];  // [v][t] slot-XOR swizzled, t = 128
    __shared__ u16t Rlo[16 * 128];
    __shared__ u16t Uhi[16 * 128];
    __shared__ u16t Ulo[16 * 128];

    const int t = threadIdx.x, l = t & 63, w = t >> 6;   // w: 0..7 = t-tile
    const int bh = blockIdx.x & 7, vt = blockIdx.x >> 3; // XCD affinity on bh
    const int b = bh >> 2, h = bh & 3;
    const int vcol0 = vt * 16;
    const int vlow = l & 15, g4 = l >> 4;
    const int sw = vlow & 7;
    const int isHi = (w >= 4);
    const int w4 = isHi ? (w - 4) : w;

    for (int i = t; i < 16 * 256; i += 512) { Shi[i] = 0; Slo[i] = 0; }
    f32x4 sf[2];
    sf[0] = (f32x4){0.f, 0.f, 0.f, 0.f};
    sf[1] = (f32x4){0.f, 0.f, 0.f, 0.f};

    bf16x8 kf[8], qf[8], tfh[4], tfl[4], af[4], kcf[2][4];
    u16t vfb[4];
    float bta[4];

    auto loadKQ = [&](int c) {
        const size_t rb = (size_t)(b * 2048 + c * 128 + 16 * w + vlow) * 1024 + h * 256 + g4 * 8;
#pragma unroll
        for (int ks = 0; ks < 8; ++ks) {
            kf[ks] = *(const bf16x8*)(kcb + rb + ks * 32);
            qf[ks] = *(const bf16x8*)(qcb + rb + ks * 32);
        }
    };
    auto loadVB = [&](int c) {
        const int r0 = b * 2048 + c * 128 + 16 * w + 4 * g4;
#pragma unroll
        for (int rg = 0; rg < 4; ++rg) {
            vfb[rg] = vcb[(size_t)(r0 + rg) * 1024 + h * 256 + vcol0 + vlow];
            bta[rg] = beta[(size_t)(r0 + rg) * 4 + h];
        }
    };
    auto loadT = [&](int c) {
        if (!isHi) {
            const size_t bs = (size_t)(bh * 32 + 2 * c) * 4096 + (size_t)(16 * w + vlow) * 64 + g4 * 8;
            tfh[0] = *(const bf16x8*)(TghiG + bs);
            tfh[1] = *(const bf16x8*)(TghiG + bs + 32);
            tfl[0] = *(const bf16x8*)(TgloG + bs);
            tfl[1] = *(const bf16x8*)(TgloG + bs + 32);
        } else {
            const size_t b21 = (size_t)(bh * 16 + c) * 4096 + (size_t)(16 * w4 + vlow) * 64 + g4 * 8;
            tfh[0] = *(const bf16x8*)(T21hi + b21);
            tfh[1] = *(const bf16x8*)(T21hi + b21 + 32);
            tfl[0] = *(const bf16x8*)(T21lo + b21);
            tfl[1] = *(const bf16x8*)(T21lo + b21 + 32);
            const size_t b22 = (size_t)(bh * 32 + 2 * c + 1) * 4096 + (size_t)(16 * w4 + vlow) * 64 + g4 * 8;
            tfh[2] = *(const bf16x8*)(TghiG + b22);
            tfh[3] = *(const bf16x8*)(TghiG + b22 + 32);
            tfl[2] = *(const bf16x8*)(TgloG + b22);
            tfl[3] = *(const bf16x8*)(TgloG + b22 + 32);
        }
    };
    auto loadA = [&](int c) {
        if (!isHi) {
            const size_t bs = (size_t)(bh * 32 + 2 * c) * 4096 + (size_t)(16 * w + vlow) * 64 + g4 * 8;
            af[0] = *(const bf16x8*)(AgbG + bs);
            af[1] = *(const bf16x8*)(AgbG + bs + 32);
        } else {
            const size_t b21 = (size_t)(bh * 16 + c) * 4096 + (size_t)(16 * w4 + vlow) * 64 + g4 * 8;
            af[0] = *(const bf16x8*)(A21g + b21);
            af[1] = *(const bf16x8*)(A21g + b21 + 32);
            const size_t b22 = (size_t)(bh * 32 + 2 * c + 1) * 4096 + (size_t)(16 * w4 + vlow) * 64 + g4 * 8;
            af[2] = *(const bf16x8*)(AgbG + b22);
            af[3] = *(const bf16x8*)(AgbG + b22 + 32);
        }
    };
    auto loadKC = [&](int c) {
#pragma unroll
        for (int q2 = 0; q2 < 2; ++q2) {
            const size_t cb2 = ((size_t)bh * 256 + 32 * w + 16 * q2 + vlow) * 2048 + c * 128 + g4 * 8;
#pragma unroll
            for (int ks = 0; ks < 4; ++ks)
                kcf[q2][ks] = *(const bf16x8*)(ktr + cb2 + ks * 32);
        }
    };

    loadKQ(0); loadVB(0); loadT(0); loadA(0); loadKC(0);
    __syncthreads();

    for (int c = 0; c < NMC; ++c) {
        const int cn = (c + 1 < NMC) ? c + 1 : c;
        const int trow0 = b * 2048 + c * 128;

        // ---- phase A: W = K*(Shi+Slo); O1 = Q*(Shi+Slo) ----
        f32x4 Wacc = (f32x4){0.f, 0.f, 0.f, 0.f};
        f32x4 O1   = (f32x4){0.f, 0.f, 0.f, 0.f};
#pragma unroll
        for (int ks = 0; ks < 8; ++ks) {
            const int pb = (((ks * 4 + g4) ^ sw) << 3);
            bf16x8 bH = *(const bf16x8*)&Shi[vlow * 256 + pb];
            bf16x8 bL = *(const bf16x8*)&Slo[vlow * 256 + pb];
            Wacc = MFMA(kf[ks], bH, Wacc); Wacc = MFMA(kf[ks], bL, Wacc);
            O1   = MFMA(qf[ks], bH, O1);   O1   = MFMA(qf[ks], bL, O1);
        }
        // R = beta*(V - W) -> LDS hi/lo
        {
            const int tslot = 2 * w + (g4 >> 1);             // 0..15
            const int base = vlow * 128 + ((tslot ^ sw) << 3) + ((g4 & 1) << 2);
            u16t rh[4], rl[4];
#pragma unroll
            for (int rg = 0; rg < 4; ++rg) {
                float rv = bta[rg] * (bf2f(vfb[rg]) - Wacc[rg]);
                rh[rg] = f2bf(rv);
                rl[rg] = f2bf(rv - bf2f(rh[rg]));
            }
            uint2 ph, pl;
            ph.x = (u32t)rh[0] | ((u32t)rh[1] << 16); ph.y = (u32t)rh[2] | ((u32t)rh[3] << 16);
            pl.x = (u32t)rl[0] | ((u32t)rl[1] << 16); pl.y = (u32t)rl[2] | ((u32t)rl[3] << 16);
            *(uint2*)&Rhi[base] = ph;
            *(uint2*)&Rlo[base] = pl;
        }
        loadKQ(cn);
        loadVB(cn);
        __syncthreads();

        // ---- phase B: U = T128 * R  (rows<64: T11; rows>=64: T21|T22) ----
        f32x4 Uacc = (f32x4){0.f, 0.f, 0.f, 0.f};
        const int NK = isHi ? 4 : 2;
        for (int ks = 0; ks < NK; ++ks) {
            const int pb = (((ks * 4 + g4) ^ sw) << 3);
            bf16x8 bH = *(const bf16x8*)&Rhi[vlow * 128 + pb];
            bf16x8 bL = *(const bf16x8*)&Rlo[vlow * 128 + pb];
            Uacc = MFMA(tfh[ks], bH, Uacc);
            Uacc = MFMA(tfh[ks], bL, Uacc);
            Uacc = MFMA(tfl[ks], bH, Uacc);
        }
        {
            const int tslot = 2 * w + (g4 >> 1);
            const int base = vlow * 128 + ((tslot ^ sw) << 3) + ((g4 & 1) << 2);
            u16t uh[4], ul[4];
#pragma unroll
            for (int rg = 0; rg < 4; ++rg) {
                uh[rg] = f2bf(Uacc[rg]);
                ul[rg] = f2bf(Uacc[rg] - bf2f(uh[rg]));
            }
            uint2 ph, pl;
            ph.x = (u32t)uh[0] | ((u32t)uh[1] << 16); ph.y = (u32t)uh[2] | ((u32t)uh[3] << 16);
            pl.x = (u32t)ul[0] | ((u32t)ul[1] << 16); pl.y = (u32t)ul[2] | ((u32t)ul[3] << 16);
            *(uint2*)&Uhi[base] = ph;
            *(uint2*)&Ulo[base] = pl;
        }
        loadT(cn);
        __syncthreads();

        // ---- phase C: O = O1 + A128*U ; S += K^T*U ; refresh S mirror ----
        bf16x8 uhf[4], ulf[4];
#pragma unroll
        for (int ks = 0; ks < 4; ++ks) {
            const int pb = (((ks * 4 + g4) ^ sw) << 3);
            uhf[ks] = *(const bf16x8*)&Uhi[vlow * 128 + pb];
            ulf[ks] = *(const bf16x8*)&Ulo[vlow * 128 + pb];
        }
        f32x4 Oacc = O1;
        for (int ks = 0; ks < NK; ++ks) {
            Oacc = MFMA(af[ks], uhf[ks], Oacc);
            Oacc = MFMA(af[ks], ulf[ks], Oacc);
        }
#pragma unroll
        for (int rg = 0; rg < 4; ++rg)
            o_raw[(size_t)(trow0 + 16 * w + 4 * g4 + rg) * 1024 + h * 256 + vcol0 + vlow] = f2bf(Oacc[rg]);
        loadA(cn);

#pragma unroll
        for (int q2 = 0; q2 < 2; ++q2) {
#pragma unroll
            for (int ks = 0; ks < 4; ++ks) {
                sf[q2] = MFMA(kcf[q2][ks], uhf[ks], sf[q2]);
                sf[q2] = MFMA(kcf[q2][ks], ulf[ks], sf[q2]);
            }
        }
        loadKC(cn);

        // S mirror refresh (hi/lo)
#pragma unroll
        for (int q2 = 0; q2 < 2; ++q2) {
            u16t sh[4], sl[4];
#pragma unroll
            for (int rg = 0; rg < 4; ++rg) {
                u16t hi = f2bf(sf[q2][rg]);
                sh[rg] = hi;
                sl[rg] = f2bf(sf[q2][rg] - bf2f(hi));
            }
            const int rslot = 4 * w + 2 * q2 + (g4 >> 1);    // 0..31
            const int base = vlow * 256 + ((rslot ^ sw) << 3) + ((g4 & 1) << 2);
            uint2 ph, pl;
            ph.x = (u32t)sh[0] | ((u32t)sh[1] << 16); ph.y = (u32t)sh[2] | ((u32t)sh[3] << 16);
            pl.x = (u32t)sl[0] | ((u32t)sl[1] << 16); pl.y = (u32t)sl[2] | ((u32t)sl[3] << 16);
            *(uint2*)&Shi[base] = ph;
            *(uint2*)&Slo[base] = pl;
        }
        __syncthreads();
    }
}

// =================== rms_norm (bf16 in -> bf16 out) ======================
__global__ __launch_bounds__(256) void rms_kernel(const u16t* __restrict__ in,
                                                  const float* __restrict__ w,
                                                  u16t* __restrict__ out) {
    const int gw   = (blockIdx.x * blockDim.x + threadIdx.x) >> 6;
    const int lane = threadIdx.x & 63;
    const int r = gw >> 2;
    const int h = gw & 3;
    const size_t base = (size_t)r * HIDD + h * 256 + lane * 4;
    ushort4 xv = *(const ushort4*)&in[base];
    float x0 = bf2f(xv.x), x1 = bf2f(xv.y), x2 = bf2f(xv.z), x3 = bf2f(xv.w);
    float ss = x0 * x0 + x1 * x1 + x2 * x2 + x3 * x3;
    ss = waveReduceSum(ss);
    const float sc = rsqrtf(ss * (1.0f / 256.0f) + 1e-5f);
    float4 wv = *(const float4*)&w[lane * 4];
    ushort4 o;
    o.x = f2bf(x0 * sc * wv.x); o.y = f2bf(x1 * sc * wv.y);
    o.z = f2bf(x2 * sc * wv.z); o.w = f2bf(x3 * sc * wv.w);
    *(ushort4*)&out[base] = o;
}

extern "C" void kernel_launch(void* const* d_in, const int* in_sizes, int n_in,
                              void* d_out, int out_size, void* d_ws, size_t ws_size,
                              hipStream_t stream) {
    const float* X      = (const float*)d_in[0];
    const float* Wq     = (const float*)d_in[1];
    const float* Wk     = (const float*)d_in[2];
    const float* Wv     = (const float*)d_in[3];
    const float* Wb     = (const float*)d_in[4];
    const float* conv_q = (const float*)d_in[5];
    const float* conv_k = (const float*)d_in[6];
    const float* conv_v = (const float*)d_in[7];
    const float* norm_w = (const float*)d_in[8];
    const float* Wo     = (const float*)d_in[9];
    float* out = (float*)d_out;

    char* W8 = (char*)d_ws;
    const size_t MB = 1u << 20;
    u16t* Xbf   = (u16t*)(W8 + 0 * MB);
    u16t* o_raw = Xbf;
    u16t* qpre  = (u16t*)(W8 + 8 * MB);   // dead after conv_qv:
    u16t* T21hi = (u16t*)(W8 + 8 * MB);   //   2MB (128 chunks x 64x64 bf16)
    u16t* T21lo = (u16t*)(W8 + 10 * MB);  //   2MB
    u16t* A21g  = (u16t*)(W8 + 12 * MB);  //   2MB
    u16t* o_nrm = qpre;                   // written by rms AFTER scan
    u16t* kpre  = (u16t*)(W8 + 16 * MB);
    u16t* Tghi  = (u16t*)(W8 + 16 * MB);
    u16t* Tglo  = (u16t*)(W8 + 18 * MB);
    u16t* Agb   = (u16t*)(W8 + 20 * MB);
    u16t* vpre  = (u16t*)(W8 + 24 * MB);
    u16t* ktr   = (u16t*)(W8 + 24 * MB);
    u16t* WqT   = (u16t*)(W8 + 32 * MB);
    u16t* qcb   = (u16t*)(W8 + 32 * MB);
    u16t* WkT   = (u16t*)(W8 + 40 * MB);
    u16t* kcb   = (u16t*)(W8 + 40 * MB);
    u16t* WvT   = (u16t*)(W8 + 48 * MB);
    u16t* vcb   = (u16t*)(W8 + 48 * MB);
    u16t* WoT   = (u16t*)(W8 + 56 * MB);
    float* betab = (float*)(W8 + 58 * MB);

    const size_t PL = 4194304;   // 8 MB plane stride in u16 elements

    f2bf_kernel<<<2048, 256, 0, stream>>>(X, Xbf);
    transpose_w4<<<dim3(16, 16, 4), 256, 0, stream>>>(Wq, Wk, Wv, Wo, WqT, WkT, WvT, WoT);

    gemm_mfma<<<dim3(24, 32), 256, 0, stream>>>(Xbf, WqT, nullptr, qpre, 1,
                                                ROWS, 3072, HIDD, PL, PL, 2);
    beta_kernel<<<ROWS / 4, 256, 0, stream>>>(X, Wb, betab);

    conv_qv<<<dim3(ROWS, 2), 256, 0, stream>>>(qpre, conv_q, qcb, vpre, conv_v, vcb);
    conv_k_chunk<<<256, 256, 0, stream>>>(kpre, conv_k, kcb, ktr);

    prep_kernel<<<256, 256, 0, stream>>>(qcb, kcb, betab, Tghi, Tglo, Agb);
    prep2_kernel<<<128, 256, 0, stream>>>(qcb, kcb, betab, Tghi, Tglo, T21hi, T21lo, A21g);
    scan_mfma<<<128, 512, 0, stream>>>(qcb, kcb, ktr, vcb, betab, Tghi, Tglo, Agb,
                                       T21hi, T21lo, A21g, o_raw);

    rms_kernel<<<ROWS, 256, 0, stream>>>(o_raw, norm_w, o_nrm);
    gemm_mfma<<<dim3(8, 32), 256, 0, stream>>>(o_nrm, WoT, out, nullptr, 0,
                                               ROWS, HIDD, HIDD, 0, 0, 1);
}

// Round 13
// 372.984 us; speedup vs baseline: 3.0136x; 3.0136x over previous
//
#include <hip/hip_runtime.h>
#include <math.h>

#define BB   2
#define SS   2048
#define HIDD 1024
#define ROWS 4096
#define NCH  32      // 64-row chunks (prep level)
#define CH   64
#define NMC  16      // 128-row macro-chunks (scan level)

typedef unsigned short u16t;
typedef unsigned int   u32t;

typedef __attribute__((ext_vector_type(8))) short bf16x8;
typedef __attribute__((ext_vector_type(4))) float f32x4;

__device__ __forceinline__ float bf2f(u16t u) { return __uint_as_float(((u32t)u) << 16); }
__device__ __forceinline__ u16t f2bf(float f) {
    u32t b = __float_as_uint(f);
    return (u16t)((b + 0x7FFFu + ((b >> 16) & 1u)) >> 16);
}
__device__ __forceinline__ float lo_bf(u32t u) { return __uint_as_float(u << 16); }
__device__ __forceinline__ float hi_bf(u32t u) { return __uint_as_float(u & 0xFFFF0000u); }

__device__ __forceinline__ float waveReduceSum(float v) {
#pragma unroll
    for (int m = 1; m < 64; m <<= 1) v += __shfl_xor(v, m, 64);
    return v;
}

__device__ __forceinline__ void gload16(const void* g, void* l) {
    __builtin_amdgcn_global_load_lds(
        (const __attribute__((address_space(1))) unsigned int*)g,
        (__attribute__((address_space(3))) unsigned int*)l, 16, 0, 0);
}

#define MFMA(a, b, c) __builtin_amdgcn_mfma_f32_16x16x32_bf16(a, b, c, 0, 0, 0)

// =================== X f32 -> bf16 ======================================
__global__ __launch_bounds__(256) void f2bf_kernel(const float* __restrict__ in,
                                                   u16t* __restrict__ out) {
    const size_t idx = ((size_t)blockIdx.x * 256 + threadIdx.x) * 8;
    float4 a = *(const float4*)&in[idx];
    float4 b = *(const float4*)&in[idx + 4];
    ushort4 o1, o2;
    o1.x = f2bf(a.x); o1.y = f2bf(a.y); o1.z = f2bf(a.z); o1.w = f2bf(a.w);
    o2.x = f2bf(b.x); o2.y = f2bf(b.y); o2.z = f2bf(b.z); o2.w = f2bf(b.w);
    *(ushort4*)&out[idx] = o1;
    *(ushort4*)&out[idx + 4] = o2;
}

// ====== 4 weight transposes fused in one launch (blockIdx.z selects) ======
__global__ __launch_bounds__(256) void transpose_w4(const float* __restrict__ W0,
                                                    const float* __restrict__ W1,
                                                    const float* __restrict__ W2,
                                                    const float* __restrict__ W3,
                                                    u16t* __restrict__ T0,
                                                    u16t* __restrict__ T1,
                                                    u16t* __restrict__ T2,
                                                    u16t* __restrict__ T3) {
    __shared__ u16t tile[64][65];
    const int z = blockIdx.z;
    const float* W = (z == 0) ? W0 : (z == 1) ? W1 : (z == 2) ? W2 : W3;
    u16t* WT = (z == 0) ? T0 : (z == 1) ? T1 : (z == 2) ? T2 : T3;
    const int t = threadIdx.x;
    const int r0 = blockIdx.y * 64, c0 = blockIdx.x * 64;
    const int lr = t >> 2, lc4 = (t & 3) * 16;
#pragma unroll
    for (int m = 0; m < 4; ++m) {
        float4 v = *(const float4*)&W[(size_t)(r0 + lr) * 1024 + c0 + lc4 + m * 4];
        tile[lr][lc4 + m * 4 + 0] = f2bf(v.x);
        tile[lr][lc4 + m * 4 + 1] = f2bf(v.y);
        tile[lr][lc4 + m * 4 + 2] = f2bf(v.z);
        tile[lr][lc4 + m * 4 + 3] = f2bf(v.w);
    }
    __syncthreads();
#pragma unroll
    for (int m = 0; m < 16; ++m)
        WT[(size_t)(c0 + lr) * 1024 + r0 + lc4 + m] = tile[lc4 + m][lr];
}

// ======= MFMA GEMM: C[M,N] = A[M,K] * BT[N,K]^T, plane-strided B/C =======
__global__ __launch_bounds__(256) void gemm_mfma(const u16t* __restrict__ A,
                                                 const u16t* __restrict__ BT,
                                                 float* __restrict__ Cf,
                                                 u16t* __restrict__ Cb, int obf,
                                                 int M, int N, int K,
                                                 size_t bStrideP, size_t cStrideP,
                                                 int CX) {
    __shared__ u16t As[128 * 64];
    __shared__ u16t Bs[128 * 64];
    const int t = threadIdx.x, l = t & 63, w = t >> 6;
    const int wr = w >> 1, wc = w & 1;

    const int lin = blockIdx.y * gridDim.x + blockIdx.x;
    const int xcd = lin & 7, idx = lin >> 3;
    const int Wc = gridDim.x / CX;
    const int Hc = (gridDim.y * CX) >> 3;
    const int colB = (xcd % CX) * Wc + idx % Wc;
    const int rowB = (xcd / CX) * Hc + idx / Wc;

    const int rowBase = rowB * 128, colBase = colB * 128;
    const int l15 = l & 15, g4 = l >> 4;

    const int bplane = colBase >> 10;
    const int bcol = colBase & 1023;

    const int srow = l >> 3;
    const int sj = (l & 7) ^ srow;
    const u16t* aSrc = A + (size_t)(rowBase + srow) * K + sj * 8;
    const u16t* bSrc = BT + (size_t)bplane * bStrideP + (size_t)(bcol + srow) * K + sj * 8;

    f32x4 acc[4][4];
#pragma unroll
    for (int i = 0; i < 4; ++i)
#pragma unroll
        for (int j = 0; j < 4; ++j) acc[i][j] = (f32x4){0.f, 0.f, 0.f, 0.f};

    for (int k0 = 0; k0 < K; k0 += 64) {
#pragma unroll
        for (int i = 0; i < 4; ++i) {
            const int rb = (i * 4 + w) * 8;
            gload16(aSrc + (size_t)rb * K + k0, &As[rb * 64]);
            gload16(bSrc + (size_t)rb * K + k0, &Bs[rb * 64]);
        }
        __syncthreads();
#pragma unroll
        for (int kh = 0; kh < 2; ++kh) {
            bf16x8 aF[4], bF[4];
#pragma unroll
            for (int mi = 0; mi < 4; ++mi) {
                const int row = wr * 64 + mi * 16 + l15;
                const int phys = (kh * 4 + g4) ^ (row & 7);
                aF[mi] = *(const bf16x8*)&As[row * 64 + phys * 8];
            }
#pragma unroll
            for (int ni = 0; ni < 4; ++ni) {
                const int row = wc * 64 + ni * 16 + l15;
                const int phys = (kh * 4 + g4) ^ (row & 7);
                bF[ni] = *(const bf16x8*)&Bs[row * 64 + phys * 8];
            }
#pragma unroll
            for (int mi = 0; mi < 4; ++mi)
#pragma unroll
                for (int ni = 0; ni < 4; ++ni)
                    acc[mi][ni] = MFMA(aF[mi], bF[ni], acc[mi][ni]);
        }
        __syncthreads();
    }
#pragma unroll
    for (int mi = 0; mi < 4; ++mi)
#pragma unroll
        for (int ni = 0; ni < 4; ++ni)
#pragma unroll
            for (int rg = 0; rg < 4; ++rg) {
                const int row = rowBase + wr * 64 + mi * 16 + g4 * 4 + rg;
                const int col = colBase + wc * 64 + ni * 16 + l15;
                const int plane = col >> 10, cc = col & 1023;
                const float v = acc[mi][ni][rg];
                if (obf) Cb[(size_t)plane * cStrideP + (size_t)row * 1024 + cc] = f2bf(v);
                else     Cf[(size_t)plane * cStrideP + (size_t)row * 1024 + cc] = v;
            }
}

// =================== beta = sigmoid(X @ Wb) ==============================
__global__ __launch_bounds__(256) void beta_kernel(const float* __restrict__ X,
                                                   const float* __restrict__ Wb,
                                                   float* __restrict__ beta) {
    const int gw   = (blockIdx.x * blockDim.x + threadIdx.x) >> 6;
    const int lane = threadIdx.x & 63;
    if (gw >= ROWS) return;
    const float* x = X + (size_t)gw * HIDD;
    float a0 = 0.f, a1 = 0.f, a2 = 0.f, a3 = 0.f;
#pragma unroll
    for (int i = 0; i < 4; ++i) {
        const int k = lane * 16 + i * 4;
        float4 xv = *(const float4*)&x[k];
        float4 w0 = *(const float4*)&Wb[(size_t)(k + 0) * 4];
        float4 w1 = *(const float4*)&Wb[(size_t)(k + 1) * 4];
        float4 w2 = *(const float4*)&Wb[(size_t)(k + 2) * 4];
        float4 w3 = *(const float4*)&Wb[(size_t)(k + 3) * 4];
        a0 += xv.x * w0.x + xv.y * w1.x + xv.z * w2.x + xv.w * w3.x;
        a1 += xv.x * w0.y + xv.y * w1.y + xv.z * w2.y + xv.w * w3.y;
        a2 += xv.x * w0.z + xv.y * w1.z + xv.z * w2.z + xv.w * w3.z;
        a3 += xv.x * w0.w + xv.y * w1.w + xv.z * w2.w + xv.w * w3.w;
    }
    a0 = waveReduceSum(a0); a1 = waveReduceSum(a1);
    a2 = waveReduceSum(a2); a3 = waveReduceSum(a3);
    if (lane == 0) {
        float4 o = make_float4(1.f / (1.f + expf(-a0)), 1.f / (1.f + expf(-a1)),
                               1.f / (1.f + expf(-a2)), 1.f / (1.f + expf(-a3)));
        *(float4*)&beta[(size_t)gw * 4] = o;
    }
}

// == causal conv(K=4)+silu(+l2norm), q & v fused in one launch (blockIdx.y) ==
__global__ __launch_bounds__(256) void conv_qv(const u16t* __restrict__ inQ,
                                               const float* __restrict__ wQ,
                                               u16t* __restrict__ outQ,
                                               const u16t* __restrict__ inV,
                                               const float* __restrict__ wV,
                                               u16t* __restrict__ outV) {
    const int isQ = (blockIdx.y == 0);
    const u16t* in = isQ ? inQ : inV;
    const float* w = isQ ? wQ : wV;
    u16t* out      = isQ ? outQ : outV;
    const int doL2 = isQ;

    const int gw   = (blockIdx.x * blockDim.x + threadIdx.x) >> 6;
    const int lane = threadIdx.x & 63;
    const int r = gw >> 2;
    const int h = gw & 3;
    const int b = r >> 11;
    const int s = r & 2047;
    const int c4 = h * 256 + lane * 4;

    const float4 wr0 = *(const float4*)&w[(size_t)(c4 + 0) * 4];
    const float4 wr1 = *(const float4*)&w[(size_t)(c4 + 1) * 4];
    const float4 wr2 = *(const float4*)&w[(size_t)(c4 + 2) * 4];
    const float4 wr3 = *(const float4*)&w[(size_t)(c4 + 3) * 4];

    const size_t rowB = (size_t)(b << 11);
    float x0[4] = {0, 0, 0, 0}, x1[4] = {0, 0, 0, 0}, x2[4] = {0, 0, 0, 0}, x3[4];
    ushort4 u;
    if (s >= 3) { u = *(const ushort4*)&in[(rowB + s - 3) * HIDD + c4];
        x0[0] = bf2f(u.x); x0[1] = bf2f(u.y); x0[2] = bf2f(u.z); x0[3] = bf2f(u.w); }
    if (s >= 2) { u = *(const ushort4*)&in[(rowB + s - 2) * HIDD + c4];
        x1[0] = bf2f(u.x); x1[1] = bf2f(u.y); x1[2] = bf2f(u.z); x1[3] = bf2f(u.w); }
    if (s >= 1) { u = *(const ushort4*)&in[(rowB + s - 1) * HIDD + c4];
        x2[0] = bf2f(u.x); x2[1] = bf2f(u.y); x2[2] = bf2f(u.z); x2[3] = bf2f(u.w); }
    u = *(const ushort4*)&in[(rowB + s) * HIDD + c4];
    x3[0] = bf2f(u.x); x3[1] = bf2f(u.y); x3[2] = bf2f(u.z); x3[3] = bf2f(u.w);

    float y0 = wr0.x * x0[0] + wr0.y * x1[0] + wr0.z * x2[0] + wr0.w * x3[0];
    float y1 = wr1.x * x0[1] + wr1.y * x1[1] + wr1.z * x2[1] + wr1.w * x3[1];
    float y2 = wr2.x * x0[2] + wr2.y * x1[2] + wr2.z * x2[2] + wr2.w * x3[2];
    float y3 = wr3.x * x0[3] + wr3.y * x1[3] + wr3.z * x2[3] + wr3.w * x3[3];

    y0 = y0 / (1.f + expf(-y0)); y1 = y1 / (1.f + expf(-y1));
    y2 = y2 / (1.f + expf(-y2)); y3 = y3 / (1.f + expf(-y3));

    if (doL2) {
        float ss = y0 * y0 + y1 * y1 + y2 * y2 + y3 * y3;
        ss = waveReduceSum(ss);
        float sc = rsqrtf(ss + 1e-6f);
        y0 *= sc; y1 *= sc; y2 *= sc; y3 *= sc;
    }
    ushort4 o;
    o.x = f2bf(y0); o.y = f2bf(y1); o.z = f2bf(y2); o.w = f2bf(y3);
    *(ushort4*)&out[(size_t)r * HIDD + c4] = o;
}

// ====== conv for K: row-major out + transposed ktr[bh*256+r][t] ==========
__global__ __launch_bounds__(256) void conv_k_chunk(const u16t* __restrict__ pre,
                                                    const float* __restrict__ w,
                                                    u16t* __restrict__ rowout,
                                                    u16t* __restrict__ trout) {
    const int t = threadIdx.x;
    const int bh = blockIdx.x >> 5, c = blockIdx.x & 31;
    const int b = bh >> 2, h = bh & 3;
    const int i = t >> 2, g = t & 3;
    const int s = c * 64 + i;
    const size_t row = (size_t)b * 2048 + s;
    const int ch0 = h * 256 + g * 64;
    const int cloc = g * 64;
    float y[64];
#pragma unroll
    for (int m = 0; m < 8; ++m) {
        const int cm = ch0 + m * 8;
        uint4 x3 = *(const uint4*)&pre[row * 1024 + cm];
        uint4 x2 = (s >= 1) ? *(const uint4*)&pre[(row - 1) * 1024 + cm] : make_uint4(0, 0, 0, 0);
        uint4 x1 = (s >= 2) ? *(const uint4*)&pre[(row - 2) * 1024 + cm] : make_uint4(0, 0, 0, 0);
        uint4 x0 = (s >= 3) ? *(const uint4*)&pre[(row - 3) * 1024 + cm] : make_uint4(0, 0, 0, 0);
        u32t c0[4] = {x0.x, x0.y, x0.z, x0.w};
        u32t c1[4] = {x1.x, x1.y, x1.z, x1.w};
        u32t c2[4] = {x2.x, x2.y, x2.z, x2.w};
        u32t c3[4] = {x3.x, x3.y, x3.z, x3.w};
#pragma unroll
        for (int p = 0; p < 4; ++p) {
            const int ch = m * 8 + p * 2;
            float4 wA = *(const float4*)&w[(size_t)(ch0 + ch) * 4];
            float4 wB = *(const float4*)&w[(size_t)(ch0 + ch + 1) * 4];
            float ya = wA.x * lo_bf(c0[p]) + wA.y * lo_bf(c1[p]) + wA.z * lo_bf(c2[p]) + wA.w * lo_bf(c3[p]);
            float yb = wB.x * hi_bf(c0[p]) + wB.y * hi_bf(c1[p]) + wB.z * hi_bf(c2[p]) + wB.w * hi_bf(c3[p]);
            ya = ya / (1.f + expf(-ya));
            yb = yb / (1.f + expf(-yb));
            y[ch] = ya; y[ch + 1] = yb;
        }
    }
    float ss = 0.f;
#pragma unroll
    for (int e = 0; e < 64; ++e) ss += y[e] * y[e];
    ss += __shfl_xor(ss, 1);
    ss += __shfl_xor(ss, 2);
    const float sc = rsqrtf(ss + 1e-6f);
#pragma unroll
    for (int m = 0; m < 8; ++m) {
        uint4 o;
        u32t* op = (u32t*)&o;
#pragma unroll
        for (int p = 0; p < 4; ++p) {
            u16t a = f2bf(y[m * 8 + p * 2] * sc);
            u16t bb2 = f2bf(y[m * 8 + p * 2 + 1] * sc);
            op[p] = (u32t)a | ((u32t)bb2 << 16);
        }
        *(uint4*)&rowout[row * 1024 + ch0 + m * 8] = o;
    }
#pragma unroll
    for (int e = 0; e < 64; ++e)
        trout[((size_t)bh * 256 + cloc + e) * 2048 + s] = f2bf(y[e] * sc);
}

// ====== prep: per 64-chunk T=(I+strict_lower(diag(b)KK^T))^-1 (hi/lo) =====
__global__ __launch_bounds__(256) void prep_kernel(const u16t* __restrict__ qcb,
                                                   const u16t* __restrict__ kcb,
                                                   const float* __restrict__ beta,
                                                   u16t* __restrict__ Tghi,
                                                   u16t* __restrict__ Tglo,
                                                   u16t* __restrict__ Agb) {
    __shared__ float KT[256][68];
    __shared__ float QT[256][68];
    __shared__ float Af[64][68];
    const int t = threadIdx.x;
    const int bhc = blockIdx.x;
    const int bh = bhc >> 5, c = bhc & 31;
    const int b = bh >> 2, h = bh & 3;
    const int tb = b * SS + c * CH;

    {
        const int i = t & 63, rb = t >> 6;
        const u16t* kg = kcb + (size_t)(tb + i) * HIDD + h * 256 + rb * 64;
        const u16t* qg = qcb + (size_t)(tb + i) * HIDD + h * 256 + rb * 64;
#pragma unroll
        for (int m = 0; m < 8; ++m) {
            uint4 kv = ((const uint4*)kg)[m];
            uint4 qv = ((const uint4*)qg)[m];
            u32t kw[4] = {kv.x, kv.y, kv.z, kv.w};
            u32t qw[4] = {qv.x, qv.y, qv.z, qv.w};
#pragma unroll
            for (int n = 0; n < 4; ++n) {
                int rr = rb * 64 + m * 8 + n * 2;
                KT[rr][i]     = lo_bf(kw[n]);
                KT[rr + 1][i] = hi_bf(kw[n]);
                QT[rr][i]     = lo_bf(qw[n]);
                QT[rr + 1][i] = hi_bf(qw[n]);
            }
        }
    }
    __syncthreads();

    const int it = t & 63, jb = t >> 6;
    float kk[16], qk[16];
#pragma unroll
    for (int m = 0; m < 16; ++m) { kk[m] = 0.f; qk[m] = 0.f; }
#pragma unroll 2
    for (int r = 0; r < 256; ++r) {
        float ki = KT[r][it];
        float qi = QT[r][it];
        float4 ka = *(const float4*)&KT[r][jb * 16 + 0];
        float4 kb = *(const float4*)&KT[r][jb * 16 + 4];
        float4 kc = *(const float4*)&KT[r][jb * 16 + 8];
        float4 kd = *(const float4*)&KT[r][jb * 16 + 12];
        float kj[16] = {ka.x, ka.y, ka.z, ka.w, kb.x, kb.y, kb.z, kb.w,
                        kc.x, kc.y, kc.z, kc.w, kd.x, kd.y, kd.z, kd.w};
#pragma unroll
        for (int m = 0; m < 16; ++m) { kk[m] += ki * kj[m]; qk[m] += qi * kj[m]; }
    }

    const float bta = beta[(size_t)(tb + it) * 4 + h];
    u16t* ag = Agb + (size_t)bhc * 4096 + (size_t)it * 64 + jb * 16;
#pragma unroll
    for (int m = 0; m < 16; ++m) {
        int j = jb * 16 + m;
        Af[it][j] = (j < it) ? bta * kk[m] : 0.f;
    }
#pragma unroll
    for (int m4 = 0; m4 < 4; ++m4) {
        ushort4 o;
        o.x = f2bf((jb * 16 + m4 * 4 + 0 <= it) ? qk[m4 * 4 + 0] : 0.f);
        o.y = f2bf((jb * 16 + m4 * 4 + 1 <= it) ? qk[m4 * 4 + 1] : 0.f);
        o.z = f2bf((jb * 16 + m4 * 4 + 2 <= it) ? qk[m4 * 4 + 2] : 0.f);
        o.w = f2bf((jb * 16 + m4 * 4 + 3 <= it) ? qk[m4 * 4 + 3] : 0.f);
        *(ushort4*)&ag[m4 * 4] = o;
    }
    __syncthreads();

    if (t < 64) {
        const int ccol = t;
        float tc[64];
#pragma unroll
        for (int j = 0; j < 64; ++j) tc[j] = (j == ccol) ? 1.f : 0.f;
#pragma unroll
        for (int i = 1; i < 64; ++i) {
            float a = 0.f;
#pragma unroll
            for (int j = 0; j < i; ++j) a += Af[i][j] * tc[j];
            tc[i] -= a;
        }
        u16t* th = Tghi + (size_t)bhc * 4096;
        u16t* tl = Tglo + (size_t)bhc * 4096;
#pragma unroll
        for (int i = 0; i < 64; ++i) {
            u16t hi = f2bf(tc[i]);
            th[i * 64 + ccol] = hi;
            tl[i * 64 + ccol] = f2bf(tc[i] - bf2f(hi));
        }
    }
}

// ====== prep2: per 128-macro-chunk compose T21 = -T22*G21*T11, A21 ========
__global__ __launch_bounds__(256) void prep2_kernel(const u16t* __restrict__ qcb,
                                                    const u16t* __restrict__ kcb,
                                                    const float* __restrict__ beta,
                                                    const u16t* __restrict__ Tghi,
                                                    const u16t* __restrict__ Tglo,
                                                    u16t* __restrict__ T21hi,
                                                    u16t* __restrict__ T21lo,
                                                    u16t* __restrict__ A21g) {
    __shared__ float Gs[64][68];
    __shared__ float T11f[64][68];
    __shared__ float T22f[64][68];
    __shared__ float Pf[64][68];

    const int t = threadIdx.x, l = t & 63, w = t >> 6;
    const int bhmc = blockIdx.x;
    const int bh = bhmc >> 4, mc = bhmc & 15;
    const int b = bh >> 2, h = bh & 3;
    const int t1 = b * SS + mc * 128;
    const int t2 = t1 + 64;
    const int vlow = l & 15, g4 = l >> 4;

    bf16x8 k2f[8], q2f[8];
    {
        const size_t rb = (size_t)(t2 + 16 * w + vlow) * 1024 + h * 256 + g4 * 8;
#pragma unroll
        for (int ks = 0; ks < 8; ++ks) {
            k2f[ks] = *(const bf16x8*)(kcb + rb + ks * 32);
            q2f[ks] = *(const bf16x8*)(qcb + rb + ks * 32);
        }
    }
    float bta2[4];
#pragma unroll
    for (int rg = 0; rg < 4; ++rg)
        bta2[rg] = beta[(size_t)(t2 + 16 * w + 4 * g4 + rg) * 4 + h];

#pragma unroll
    for (int jt = 0; jt < 4; ++jt) {
        bf16x8 k1f[8];
        const size_t rb1 = (size_t)(t1 + 16 * jt + vlow) * 1024 + h * 256 + g4 * 8;
#pragma unroll
        for (int ks = 0; ks < 8; ++ks)
            k1f[ks] = *(const bf16x8*)(kcb + rb1 + ks * 32);
        f32x4 Gacc = (f32x4){0.f, 0.f, 0.f, 0.f};
        f32x4 Aacc = (f32x4){0.f, 0.f, 0.f, 0.f};
#pragma unroll
        for (int ks = 0; ks < 8; ++ks) {
            Gacc = MFMA(k2f[ks], k1f[ks], Gacc);
            Aacc = MFMA(q2f[ks], k1f[ks], Aacc);
        }
        const int j = 16 * jt + vlow;
#pragma unroll
        for (int rg = 0; rg < 4; ++rg) {
            const int i = 16 * w + 4 * g4 + rg;
            Gs[i][j] = bta2[rg] * Gacc[rg];
            A21g[(size_t)bhmc * 4096 + (size_t)i * 64 + j] = f2bf(Aacc[rg]);
        }
    }
    {
        const size_t b11 = (size_t)(bh * 32 + 2 * mc) * 4096;
        const size_t b22 = (size_t)(bh * 32 + 2 * mc + 1) * 4096;
        for (int idx = t; idx < 4096; idx += 256) {
            const int i = idx >> 6, j = idx & 63;
            T11f[i][j] = bf2f(Tghi[b11 + idx]) + bf2f(Tglo[b11 + idx]);
            T22f[i][j] = bf2f(Tghi[b22 + idx]) + bf2f(Tglo[b22 + idx]);
        }
    }
    __syncthreads();

    {
        const int col = t & 63, rq = t >> 6;
        for (int ii = 0; ii < 16; ++ii) {
            const int i = rq * 16 + ii;
            float a = 0.f;
#pragma unroll 8
            for (int j = 0; j < 64; ++j) a += Gs[i][j] * T11f[j][col];
            Pf[i][col] = a;
        }
    }
    __syncthreads();

    {
        const int col = t & 63, rq = t >> 6;
        for (int ii = 0; ii < 16; ++ii) {
            const int i = rq * 16 + ii;
            float a = 0.f;
#pragma unroll 8
            for (int j = 0; j < 64; ++j) a += T22f[i][j] * Pf[j][col];
            a = -a;
            const u16t hi = f2bf(a);
            T21hi[(size_t)bhmc * 4096 + (size_t)i * 64 + col] = hi;
            T21lo[(size_t)bhmc * 4096 + (size_t)i * 64 + col] = f2bf(a - bf2f(hi));
        }
    }
}

// ====== MFMA scan v10: 128-row macro-chunks, 8 waves, STATIC indexing ======
__global__ __launch_bounds__(512, 1) void scan_mfma(const u16t* __restrict__ qcb,
                                                    const u16t* __restrict__ kcb,
                                                    const u16t* __restrict__ ktr,
                                                    const u16t* __restrict__ vcb,
                                                    const float* __restrict__ beta,
                                                    const u16t* __restrict__ TghiG,
                                                    const u16t* __restrict__ TgloG,
                                                    const u16t* __restrict__ AgbG,
                                                    const u16t* __restrict__ T21hi,
                                                    const u16t* __restrict__ T21lo,
                                                    const u16t* __restrict__ A21g,
                                                    u16t* __restrict__ o_raw) {
    __shared__ u16t Shi[16 * 256];
    __shared__ u16t Slo[16 * 256];
    __shared__ u16t Rhi[16 * 128];
    __shared__ u16t Rlo[16 * 128];
    __shared__ u16t Uhi[16 * 128];
    __shared__ u16t Ulo[16 * 128];

    const int t = threadIdx.x, l = t & 63, w = t >> 6;   // w: 0..7 = t-tile
    const int bh = blockIdx.x & 7, vt = blockIdx.x >> 3;
    const int b = bh >> 2, h = bh & 3;
    const int vcol0 = vt * 16;
    const int vlow = l & 15, g4 = l >> 4;
    const int sw = vlow & 7;
    const bool isHi = (w >= 4);
    const int w4 = isHi ? (w - 4) : w;

    for (int i = t; i < 16 * 256; i += 512) { Shi[i] = 0; Slo[i] = 0; }
    f32x4 sf[2];
    sf[0] = (f32x4){0.f, 0.f, 0.f, 0.f};
    sf[1] = (f32x4){0.f, 0.f, 0.f, 0.f};

    bf16x8 kf[8], qf[8], tfh[4], tfl[4], af[4], kcf[2][4];
    u16t vfb[4];
    float bta[4];

    auto loadKQ = [&](int c) {
        const size_t rb = (size_t)(b * 2048 + c * 128 + 16 * w + vlow) * 1024 + h * 256 + g4 * 8;
#pragma unroll
        for (int ks = 0; ks < 8; ++ks) {
            kf[ks] = *(const bf16x8*)(kcb + rb + ks * 32);
            qf[ks] = *(const bf16x8*)(qcb + rb + ks * 32);
        }
    };
    auto loadVB = [&](int c) {
        const int r0 = b * 2048 + c * 128 + 16 * w + 4 * g4;
#pragma unroll
        for (int rg = 0; rg < 4; ++rg) {
            vfb[rg] = vcb[(size_t)(r0 + rg) * 1024 + h * 256 + vcol0 + vlow];
            bta[rg] = beta[(size_t)(r0 + rg) * 4 + h];
        }
    };
    auto loadT = [&](int c) {
        if (!isHi) {
            const size_t bs = (size_t)(bh * 32 + 2 * c) * 4096 + (size_t)(16 * w + vlow) * 64 + g4 * 8;
            tfh[0] = *(const bf16x8*)(TghiG + bs);
            tfh[1] = *(const bf16x8*)(TghiG + bs + 32);
            tfl[0] = *(const bf16x8*)(TgloG + bs);
            tfl[1] = *(const bf16x8*)(TgloG + bs + 32);
        } else {
            const size_t b21 = (size_t)(bh * 16 + c) * 4096 + (size_t)(16 * w4 + vlow) * 64 + g4 * 8;
            tfh[0] = *(const bf16x8*)(T21hi + b21);
            tfh[1] = *(const bf16x8*)(T21hi + b21 + 32);
            tfl[0] = *(const bf16x8*)(T21lo + b21);
            tfl[1] = *(const bf16x8*)(T21lo + b21 + 32);
            const size_t b22 = (size_t)(bh * 32 + 2 * c + 1) * 4096 + (size_t)(16 * w4 + vlow) * 64 + g4 * 8;
            tfh[2] = *(const bf16x8*)(TghiG + b22);
            tfh[3] = *(const bf16x8*)(TghiG + b22 + 32);
            tfl[2] = *(const bf16x8*)(TgloG + b22);
            tfl[3] = *(const bf16x8*)(TgloG + b22 + 32);
        }
    };
    auto loadA = [&](int c) {
        if (!isHi) {
            const size_t bs = (size_t)(bh * 32 + 2 * c) * 4096 + (size_t)(16 * w + vlow) * 64 + g4 * 8;
            af[0] = *(const bf16x8*)(AgbG + bs);
            af[1] = *(const bf16x8*)(AgbG + bs + 32);
        } else {
            const size_t b21 = (size_t)(bh * 16 + c) * 4096 + (size_t)(16 * w4 + vlow) * 64 + g4 * 8;
            af[0] = *(const bf16x8*)(A21g + b21);
            af[1] = *(const bf16x8*)(A21g + b21 + 32);
            const size_t b22 = (size_t)(bh * 32 + 2 * c + 1) * 4096 + (size_t)(16 * w4 + vlow) * 64 + g4 * 8;
            af[2] = *(const bf16x8*)(AgbG + b22);
            af[3] = *(const bf16x8*)(AgbG + b22 + 32);
        }
    };
    auto loadKC = [&](int c) {
#pragma unroll
        for (int q2 = 0; q2 < 2; ++q2) {
            const size_t cb2 = ((size_t)bh * 256 + 32 * w + 16 * q2 + vlow) * 2048 + c * 128 + g4 * 8;
#pragma unroll
            for (int ks = 0; ks < 4; ++ks)
                kcf[q2][ks] = *(const bf16x8*)(ktr + cb2 + ks * 32);
        }
    };

    loadKQ(0); loadVB(0); loadT(0); loadA(0); loadKC(0);
    __syncthreads();

    for (int c = 0; c < NMC; ++c) {
        const int cn = (c + 1 < NMC) ? c + 1 : c;
        const int trow0 = b * 2048 + c * 128;

        // ---- phase A: W = K*(Shi+Slo); O1 = Q*(Shi+Slo) ----
        f32x4 Wacc = (f32x4){0.f, 0.f, 0.f, 0.f};
        f32x4 O1   = (f32x4){0.f, 0.f, 0.f, 0.f};
#pragma unroll
        for (int ks = 0; ks < 8; ++ks) {
            const int pb = (((ks * 4 + g4) ^ sw) << 3);
            bf16x8 bH = *(const bf16x8*)&Shi[vlow * 256 + pb];
            bf16x8 bL = *(const bf16x8*)&Slo[vlow * 256 + pb];
            Wacc = MFMA(kf[ks], bH, Wacc); Wacc = MFMA(kf[ks], bL, Wacc);
            O1   = MFMA(qf[ks], bH, O1);   O1   = MFMA(qf[ks], bL, O1);
        }
        // R = beta*(V - W) -> LDS hi/lo
        {
            const int tslot = 2 * w + (g4 >> 1);
            const int base = vlow * 128 + ((tslot ^ sw) << 3) + ((g4 & 1) << 2);
            u16t rh[4], rl[4];
#pragma unroll
            for (int rg = 0; rg < 4; ++rg) {
                float rv = bta[rg] * (bf2f(vfb[rg]) - Wacc[rg]);
                rh[rg] = f2bf(rv);
                rl[rg] = f2bf(rv - bf2f(rh[rg]));
            }
            uint2 ph, pl;
            ph.x = (u32t)rh[0] | ((u32t)rh[1] << 16); ph.y = (u32t)rh[2] | ((u32t)rh[3] << 16);
            pl.x = (u32t)rl[0] | ((u32t)rl[1] << 16); pl.y = (u32t)rl[2] | ((u32t)rl[3] << 16);
            *(uint2*)&Rhi[base] = ph;
            *(uint2*)&Rlo[base] = pl;
        }
        loadKQ(cn);
        loadVB(cn);
        __syncthreads();

        // ---- phase B: U = T128 * R (STATIC unrolled per branch) ----
        f32x4 Uacc = (f32x4){0.f, 0.f, 0.f, 0.f};
        if (isHi) {
#pragma unroll
            for (int ks = 0; ks < 4; ++ks) {
                const int pb = (((ks * 4 + g4) ^ sw) << 3);
                bf16x8 bH = *(const bf16x8*)&Rhi[vlow * 128 + pb];
                bf16x8 bL = *(const bf16x8*)&Rlo[vlow * 128 + pb];
                Uacc = MFMA(tfh[ks], bH, Uacc);
                Uacc = MFMA(tfh[ks], bL, Uacc);
                Uacc = MFMA(tfl[ks], bH, Uacc);
            }
        } else {
#pragma unroll
            for (int ks = 0; ks < 2; ++ks) {
                const int pb = (((ks * 4 + g4) ^ sw) << 3);
                bf16x8 bH = *(const bf16x8*)&Rhi[vlow * 128 + pb];
                bf16x8 bL = *(const bf16x8*)&Rlo[vlow * 128 + pb];
                Uacc = MFMA(tfh[ks], bH, Uacc);
                Uacc = MFMA(tfh[ks], bL, Uacc);
                Uacc = MFMA(tfl[ks], bH, Uacc);
            }
        }
        {
            const int tslot = 2 * w + (g4 >> 1);
            const int base = vlow * 128 + ((tslot ^ sw) << 3) + ((g4 & 1) << 2);
            u16t uh[4], ul[4];
#pragma unroll
            for (int rg = 0; rg < 4; ++rg) {
                uh[rg] = f2bf(Uacc[rg]);
                ul[rg] = f2bf(Uacc[rg] - bf2f(uh[rg]));
            }
            uint2 ph, pl;
            ph.x = (u32t)uh[0] | ((u32t)uh[1] << 16); ph.y = (u32t)uh[2] | ((u32t)uh[3] << 16);
            pl.x = (u32t)ul[0] | ((u32t)ul[1] << 16); pl.y = (u32t)ul[2] | ((u32t)ul[3] << 16);
            *(uint2*)&Uhi[base] = ph;
            *(uint2*)&Ulo[base] = pl;
        }
        loadT(cn);
        __syncthreads();

        // ---- phase C: O = O1 + A128*U ; S += K^T*U (STATIC unrolled) ----
        bf16x8 uhf[4], ulf[4];
#pragma unroll
        for (int ks = 0; ks < 4; ++ks) {
            const int pb = (((ks * 4 + g4) ^ sw) << 3);
            uhf[ks] = *(const bf16x8*)&Uhi[vlow * 128 + pb];
            ulf[ks] = *(const bf16x8*)&Ulo[vlow * 128 + pb];
        }
        f32x4 Oacc = O1;
        if (isHi) {
#pragma unroll
            for (int ks = 0; ks < 4; ++ks) {
                Oacc = MFMA(af[ks], uhf[ks], Oacc);
                Oacc = MFMA(af[ks], ulf[ks], Oacc);
            }
        } else {
#pragma unroll
            for (int ks = 0; ks < 2; ++ks) {
                Oacc = MFMA(af[ks], uhf[ks], Oacc);
                Oacc = MFMA(af[ks], ulf[ks], Oacc);
            }
        }
#pragma unroll
        for (int rg = 0; rg < 4; ++rg)
            o_raw[(size_t)(trow0 + 16 * w + 4 * g4 + rg) * 1024 + h * 256 + vcol0 + vlow] = f2bf(Oacc[rg]);
        loadA(cn);

#pragma unroll
        for (int q2 = 0; q2 < 2; ++q2) {
#pragma unroll
            for (int ks = 0; ks < 4; ++ks) {
                sf[q2] = MFMA(kcf[q2][ks], uhf[ks], sf[q2]);
                sf[q2] = MFMA(kcf[q2][ks], ulf[ks], sf[q2]);
            }
        }
        loadKC(cn);

        // S mirror refresh (hi/lo)
#pragma unroll
        for (int q2 = 0; q2 < 2; ++q2) {
            u16t sh[4], sl[4];
#pragma unroll
            for (int rg = 0; rg < 4; ++rg) {
                u16t hi = f2bf(sf[q2][rg]);
                sh[rg] = hi;
                sl[rg] = f2bf(sf[q2][rg] - bf2f(hi));
            }
            const int rslot = 4 * w + 2 * q2 + (g4 >> 1);
            const int base = vlow * 256 + ((rslot ^ sw) << 3) + ((g4 & 1) << 2);
            uint2 ph, pl;
            ph.x = (u32t)sh[0] | ((u32t)sh[1] << 16); ph.y = (u32t)sh[2] | ((u32t)sh[3] << 16);
            pl.x = (u32t)sl[0] | ((u32t)sl[1] << 16); pl.y = (u32t)sl[2] | ((u32t)sl[3] << 16);
            *(uint2*)&Shi[base] = ph;
            *(uint2*)&Slo[base] = pl;
        }
        __syncthreads();
    }
}

// =================== rms_norm (bf16 in -> bf16 out) ======================
__global__ __launch_bounds__(256) void rms_kernel(const u16t* __restrict__ in,
                                                  const float* __restrict__ w,
                                                  u16t* __restrict__ out) {
    const int gw   = (blockIdx.x * blockDim.x + threadIdx.x) >> 6;
    const int lane = threadIdx.x & 63;
    const int r = gw >> 2;
    const int h = gw & 3;
    const size_t base = (size_t)r * HIDD + h * 256 + lane * 4;
    ushort4 xv = *(const ushort4*)&in[base];
    float x0 = bf2f(xv.x), x1 = bf2f(xv.y), x2 = bf2f(xv.z), x3 = bf2f(xv.w);
    float ss = x0 * x0 + x1 * x1 + x2 * x2 + x3 * x3;
    ss = waveReduceSum(ss);
    const float sc = rsqrtf(ss * (1.0f / 256.0f) + 1e-5f);
    float4 wv = *(const float4*)&w[lane * 4];
    ushort4 o;
    o.x = f2bf(x0 * sc * wv.x); o.y = f2bf(x1 * sc * wv.y);
    o.z = f2bf(x2 * sc * wv.z); o.w = f2bf(x3 * sc * wv.w);
    *(ushort4*)&out[base] = o;
}

extern "C" void kernel_launch(void* const* d_in, const int* in_sizes, int n_in,
                              void* d_out, int out_size, void* d_ws, size_t ws_size,
                              hipStream_t stream) {
    const float* X      = (const float*)d_in[0];
    const float* Wq     = (const float*)d_in[1];
    const float* Wk     = (const float*)d_in[2];
    const float* Wv     = (const float*)d_in[3];
    const float* Wb     = (const float*)d_in[4];
    const float* conv_q = (const float*)d_in[5];
    const float* conv_k = (const float*)d_in[6];
    const float* conv_v = (const float*)d_in[7];
    const float* norm_w = (const float*)d_in[8];
    const float* Wo     = (const float*)d_in[9];
    float* out = (float*)d_out;

    char* W8 = (char*)d_ws;
    const size_t MB = 1u << 20;
    u16t* Xbf   = (u16t*)(W8 + 0 * MB);
    u16t* o_raw = Xbf;
    u16t* qpre  = (u16t*)(W8 + 8 * MB);
    u16t* T21hi = (u16t*)(W8 + 8 * MB);
    u16t* T21lo = (u16t*)(W8 + 10 * MB);
    u16t* A21g  = (u16t*)(W8 + 12 * MB);
    u16t* o_nrm = qpre;
    u16t* kpre  = (u16t*)(W8 + 16 * MB);
    u16t* Tghi  = (u16t*)(W8 + 16 * MB);
    u16t* Tglo  = (u16t*)(W8 + 18 * MB);
    u16t* Agb   = (u16t*)(W8 + 20 * MB);
    u16t* vpre  = (u16t*)(W8 + 24 * MB);
    u16t* ktr   = (u16t*)(W8 + 24 * MB);
    u16t* WqT   = (u16t*)(W8 + 32 * MB);
    u16t* qcb   = (u16t*)(W8 + 32 * MB);
    u16t* WkT   = (u16t*)(W8 + 40 * MB);
    u16t* kcb   = (u16t*)(W8 + 40 * MB);
    u16t* WvT   = (u16t*)(W8 + 48 * MB);
    u16t* vcb   = (u16t*)(W8 + 48 * MB);
    u16t* WoT   = (u16t*)(W8 + 56 * MB);
    float* betab = (float*)(W8 + 58 * MB);

    const size_t PL = 4194304;   // 8 MB plane stride in u16 elements

    f2bf_kernel<<<2048, 256, 0, stream>>>(X, Xbf);
    transpose_w4<<<dim3(16, 16, 4), 256, 0, stream>>>(Wq, Wk, Wv, Wo, WqT, WkT, WvT, WoT);

    gemm_mfma<<<dim3(24, 32), 256, 0, stream>>>(Xbf, WqT, nullptr, qpre, 1,
                                                ROWS, 3072, HIDD, PL, PL, 2);
    beta_kernel<<<ROWS / 4, 256, 0, stream>>>(X, Wb, betab);

    conv_qv<<<dim3(ROWS, 2), 256, 0, stream>>>(qpre, conv_q, qcb, vpre, conv_v, vcb);
    conv_k_chunk<<<256, 256, 0, stream>>>(kpre, conv_k, kcb, ktr);

    prep_kernel<<<256, 256, 0, stream>>>(qcb, kcb, betab, Tghi, Tglo, Agb);
    prep2_kernel<<<128, 256, 0, stream>>>(qcb, kcb, betab, Tghi, Tglo, T21hi, T21lo, A21g);
    scan_mfma<<<128, 512, 0, stream>>>(qcb, kcb, ktr, vcb, betab, Tghi, Tglo, Agb,
                                       T21hi, T21lo, A21g, o_raw);

    rms_kernel<<<ROWS, 256, 0, stream>>>(o_raw, norm_w, o_nrm);
    gemm_mfma<<<dim3(8, 32), 256, 0, stream>>>(o_nrm, WoT, out, nullptr, 0,
                                               ROWS, HIDD, HIDD, 0, 0, 1);
}

// Round 14
// 341.729 us; speedup vs baseline: 3.2892x; 1.0915x over previous
//
#include <hip/hip_runtime.h>
#include <math.h>

#define BB   2
#define SS   2048
#define HIDD 1024
#define ROWS 4096
#define NCH  32      // 64-row chunks (prep level)
#define CH   64
#define NMC  16      // 128-row macro-chunks (scan level)

typedef unsigned short u16t;
typedef unsigned int   u32t;

typedef __attribute__((ext_vector_type(8))) short bf16x8;
typedef __attribute__((ext_vector_type(4))) float f32x4;

__device__ __forceinline__ float bf2f(u16t u) { return __uint_as_float(((u32t)u) << 16); }
__device__ __forceinline__ u16t f2bf(float f) {
    u32t b = __float_as_uint(f);
    return (u16t)((b + 0x7FFFu + ((b >> 16) & 1u)) >> 16);
}
__device__ __forceinline__ float lo_bf(u32t u) { return __uint_as_float(u << 16); }
__device__ __forceinline__ float hi_bf(u32t u) { return __uint_as_float(u & 0xFFFF0000u); }

__device__ __forceinline__ float waveReduceSum(float v) {
#pragma unroll
    for (int m = 1; m < 64; m <<= 1) v += __shfl_xor(v, m, 64);
    return v;
}

__device__ __forceinline__ void gload16(const void* g, void* l) {
    __builtin_amdgcn_global_load_lds(
        (const __attribute__((address_space(1))) unsigned int*)g,
        (__attribute__((address_space(3))) unsigned int*)l, 16, 0, 0);
}

#define MFMA(a, b, c) __builtin_amdgcn_mfma_f32_16x16x32_bf16(a, b, c, 0, 0, 0)

// =================== X f32 -> bf16 ======================================
__global__ __launch_bounds__(256) void f2bf_kernel(const float* __restrict__ in,
                                                   u16t* __restrict__ out) {
    const size_t idx = ((size_t)blockIdx.x * 256 + threadIdx.x) * 8;
    float4 a = *(const float4*)&in[idx];
    float4 b = *(const float4*)&in[idx + 4];
    ushort4 o1, o2;
    o1.x = f2bf(a.x); o1.y = f2bf(a.y); o1.z = f2bf(a.z); o1.w = f2bf(a.w);
    o2.x = f2bf(b.x); o2.y = f2bf(b.y); o2.z = f2bf(b.z); o2.w = f2bf(b.w);
    *(ushort4*)&out[idx] = o1;
    *(ushort4*)&out[idx + 4] = o2;
}

// ====== 4 weight transposes fused in one launch (blockIdx.z selects) ======
__global__ __launch_bounds__(256) void transpose_w4(const float* __restrict__ W0,
                                                    const float* __restrict__ W1,
                                                    const float* __restrict__ W2,
                                                    const float* __restrict__ W3,
                                                    u16t* __restrict__ T0,
                                                    u16t* __restrict__ T1,
                                                    u16t* __restrict__ T2,
                                                    u16t* __restrict__ T3) {
    __shared__ u16t tile[64][65];
    const int z = blockIdx.z;
    const float* W = (z == 0) ? W0 : (z == 1) ? W1 : (z == 2) ? W2 : W3;
    u16t* WT = (z == 0) ? T0 : (z == 1) ? T1 : (z == 2) ? T2 : T3;
    const int t = threadIdx.x;
    const int r0 = blockIdx.y * 64, c0 = blockIdx.x * 64;
    const int lr = t >> 2, lc4 = (t & 3) * 16;
#pragma unroll
    for (int m = 0; m < 4; ++m) {
        float4 v = *(const float4*)&W[(size_t)(r0 + lr) * 1024 + c0 + lc4 + m * 4];
        tile[lr][lc4 + m * 4 + 0] = f2bf(v.x);
        tile[lr][lc4 + m * 4 + 1] = f2bf(v.y);
        tile[lr][lc4 + m * 4 + 2] = f2bf(v.z);
        tile[lr][lc4 + m * 4 + 3] = f2bf(v.w);
    }
    __syncthreads();
#pragma unroll
    for (int m = 0; m < 16; ++m)
        WT[(size_t)(c0 + lr) * 1024 + r0 + lc4 + m] = tile[lc4 + m][lr];
}

// ======= MFMA GEMM: C[M,N] = A[M,K] * BT[N,K]^T, plane-strided B/C =======
__global__ __launch_bounds__(256) void gemm_mfma(const u16t* __restrict__ A,
                                                 const u16t* __restrict__ BT,
                                                 float* __restrict__ Cf,
                                                 u16t* __restrict__ Cb, int obf,
                                                 int M, int N, int K,
                                                 size_t bStrideP, size_t cStrideP,
                                                 int CX) {
    __shared__ u16t As[128 * 64];
    __shared__ u16t Bs[128 * 64];
    const int t = threadIdx.x, l = t & 63, w = t >> 6;
    const int wr = w >> 1, wc = w & 1;

    const int lin = blockIdx.y * gridDim.x + blockIdx.x;
    const int xcd = lin & 7, idx = lin >> 3;
    const int Wc = gridDim.x / CX;
    const int Hc = (gridDim.y * CX) >> 3;
    const int colB = (xcd % CX) * Wc + idx % Wc;
    const int rowB = (xcd / CX) * Hc + idx / Wc;

    const int rowBase = rowB * 128, colBase = colB * 128;
    const int l15 = l & 15, g4 = l >> 4;

    const int bplane = colBase >> 10;
    const int bcol = colBase & 1023;

    const int srow = l >> 3;
    const int sj = (l & 7) ^ srow;
    const u16t* aSrc = A + (size_t)(rowBase + srow) * K + sj * 8;
    const u16t* bSrc = BT + (size_t)bplane * bStrideP + (size_t)(bcol + srow) * K + sj * 8;

    f32x4 acc[4][4];
#pragma unroll
    for (int i = 0; i < 4; ++i)
#pragma unroll
        for (int j = 0; j < 4; ++j) acc[i][j] = (f32x4){0.f, 0.f, 0.f, 0.f};

    for (int k0 = 0; k0 < K; k0 += 64) {
#pragma unroll
        for (int i = 0; i < 4; ++i) {
            const int rb = (i * 4 + w) * 8;
            gload16(aSrc + (size_t)rb * K + k0, &As[rb * 64]);
            gload16(bSrc + (size_t)rb * K + k0, &Bs[rb * 64]);
        }
        __syncthreads();
#pragma unroll
        for (int kh = 0; kh < 2; ++kh) {
            bf16x8 aF[4], bF[4];
#pragma unroll
            for (int mi = 0; mi < 4; ++mi) {
                const int row = wr * 64 + mi * 16 + l15;
                const int phys = (kh * 4 + g4) ^ (row & 7);
                aF[mi] = *(const bf16x8*)&As[row * 64 + phys * 8];
            }
#pragma unroll
            for (int ni = 0; ni < 4; ++ni) {
                const int row = wc * 64 + ni * 16 + l15;
                const int phys = (kh * 4 + g4) ^ (row & 7);
                bF[ni] = *(const bf16x8*)&Bs[row * 64 + phys * 8];
            }
#pragma unroll
            for (int mi = 0; mi < 4; ++mi)
#pragma unroll
                for (int ni = 0; ni < 4; ++ni)
                    acc[mi][ni] = MFMA(aF[mi], bF[ni], acc[mi][ni]);
        }
        __syncthreads();
    }
#pragma unroll
    for (int mi = 0; mi < 4; ++mi)
#pragma unroll
        for (int ni = 0; ni < 4; ++ni)
#pragma unroll
            for (int rg = 0; rg < 4; ++rg) {
                const int row = rowBase + wr * 64 + mi * 16 + g4 * 4 + rg;
                const int col = colBase + wc * 64 + ni * 16 + l15;
                const int plane = col >> 10, cc = col & 1023;
                const float v = acc[mi][ni][rg];
                if (obf) Cb[(size_t)plane * cStrideP + (size_t)row * 1024 + cc] = f2bf(v);
                else     Cf[(size_t)plane * cStrideP + (size_t)row * 1024 + cc] = v;
            }
}

// =================== beta = sigmoid(X @ Wb) ==============================
__global__ __launch_bounds__(256) void beta_kernel(const float* __restrict__ X,
                                                   const float* __restrict__ Wb,
                                                   float* __restrict__ beta) {
    const int gw   = (blockIdx.x * blockDim.x + threadIdx.x) >> 6;
    const int lane = threadIdx.x & 63;
    if (gw >= ROWS) return;
    const float* x = X + (size_t)gw * HIDD;
    float a0 = 0.f, a1 = 0.f, a2 = 0.f, a3 = 0.f;
#pragma unroll
    for (int i = 0; i < 4; ++i) {
        const int k = lane * 16 + i * 4;
        float4 xv = *(const float4*)&x[k];
        float4 w0 = *(const float4*)&Wb[(size_t)(k + 0) * 4];
        float4 w1 = *(const float4*)&Wb[(size_t)(k + 1) * 4];
        float4 w2 = *(const float4*)&Wb[(size_t)(k + 2) * 4];
        float4 w3 = *(const float4*)&Wb[(size_t)(k + 3) * 4];
        a0 += xv.x * w0.x + xv.y * w1.x + xv.z * w2.x + xv.w * w3.x;
        a1 += xv.x * w0.y + xv.y * w1.y + xv.z * w2.y + xv.w * w3.y;
        a2 += xv.x * w0.z + xv.y * w1.z + xv.z * w2.z + xv.w * w3.z;
        a3 += xv.x * w0.w + xv.y * w1.w + xv.z * w2.w + xv.w * w3.w;
    }
    a0 = waveReduceSum(a0); a1 = waveReduceSum(a1);
    a2 = waveReduceSum(a2); a3 = waveReduceSum(a3);
    if (lane == 0) {
        float4 o = make_float4(1.f / (1.f + expf(-a0)), 1.f / (1.f + expf(-a1)),
                               1.f / (1.f + expf(-a2)), 1.f / (1.f + expf(-a3)));
        *(float4*)&beta[(size_t)gw * 4] = o;
    }
}

// == causal conv(K=4)+silu(+l2norm), q & v fused in one launch (blockIdx.y) ==
__global__ __launch_bounds__(256) void conv_qv(const u16t* __restrict__ inQ,
                                               const float* __restrict__ wQ,
                                               u16t* __restrict__ outQ,
                                               const u16t* __restrict__ inV,
                                               const float* __restrict__ wV,
                                               u16t* __restrict__ outV) {
    const int isQ = (blockIdx.y == 0);
    const u16t* in = isQ ? inQ : inV;
    const float* w = isQ ? wQ : wV;
    u16t* out      = isQ ? outQ : outV;
    const int doL2 = isQ;

    const int gw   = (blockIdx.x * blockDim.x + threadIdx.x) >> 6;
    const int lane = threadIdx.x & 63;
    const int r = gw >> 2;
    const int h = gw & 3;
    const int b = r >> 11;
    const int s = r & 2047;
    const int c4 = h * 256 + lane * 4;

    const float4 wr0 = *(const float4*)&w[(size_t)(c4 + 0) * 4];
    const float4 wr1 = *(const float4*)&w[(size_t)(c4 + 1) * 4];
    const float4 wr2 = *(const float4*)&w[(size_t)(c4 + 2) * 4];
    const float4 wr3 = *(const float4*)&w[(size_t)(c4 + 3) * 4];

    const size_t rowB = (size_t)(b << 11);
    float x0[4] = {0, 0, 0, 0}, x1[4] = {0, 0, 0, 0}, x2[4] = {0, 0, 0, 0}, x3[4];
    ushort4 u;
    if (s >= 3) { u = *(const ushort4*)&in[(rowB + s - 3) * HIDD + c4];
        x0[0] = bf2f(u.x); x0[1] = bf2f(u.y); x0[2] = bf2f(u.z); x0[3] = bf2f(u.w); }
    if (s >= 2) { u = *(const ushort4*)&in[(rowB + s - 2) * HIDD + c4];
        x1[0] = bf2f(u.x); x1[1] = bf2f(u.y); x1[2] = bf2f(u.z); x1[3] = bf2f(u.w); }
    if (s >= 1) { u = *(const ushort4*)&in[(rowB + s - 1) * HIDD + c4];
        x2[0] = bf2f(u.x); x2[1] = bf2f(u.y); x2[2] = bf2f(u.z); x2[3] = bf2f(u.w); }
    u = *(const ushort4*)&in[(rowB + s) * HIDD + c4];
    x3[0] = bf2f(u.x); x3[1] = bf2f(u.y); x3[2] = bf2f(u.z); x3[3] = bf2f(u.w);

    float y0 = wr0.x * x0[0] + wr0.y * x1[0] + wr0.z * x2[0] + wr0.w * x3[0];
    float y1 = wr1.x * x0[1] + wr1.y * x1[1] + wr1.z * x2[1] + wr1.w * x3[1];
    float y2 = wr2.x * x0[2] + wr2.y * x1[2] + wr2.z * x2[2] + wr2.w * x3[2];
    float y3 = wr3.x * x0[3] + wr3.y * x1[3] + wr3.z * x2[3] + wr3.w * x3[3];

    y0 = y0 / (1.f + expf(-y0)); y1 = y1 / (1.f + expf(-y1));
    y2 = y2 / (1.f + expf(-y2)); y3 = y3 / (1.f + expf(-y3));

    if (doL2) {
        float ss = y0 * y0 + y1 * y1 + y2 * y2 + y3 * y3;
        ss = waveReduceSum(ss);
        float sc = rsqrtf(ss + 1e-6f);
        y0 *= sc; y1 *= sc; y2 *= sc; y3 *= sc;
    }
    ushort4 o;
    o.x = f2bf(y0); o.y = f2bf(y1); o.z = f2bf(y2); o.w = f2bf(y3);
    *(ushort4*)&out[(size_t)r * HIDD + c4] = o;
}

// ====== conv for K: row-major out + transposed ktr[bh*256+r][t] ==========
__global__ __launch_bounds__(256) void conv_k_chunk(const u16t* __restrict__ pre,
                                                    const float* __restrict__ w,
                                                    u16t* __restrict__ rowout,
                                                    u16t* __restrict__ trout) {
    const int t = threadIdx.x;
    const int bh = blockIdx.x >> 5, c = blockIdx.x & 31;
    const int b = bh >> 2, h = bh & 3;
    const int i = t >> 2, g = t & 3;
    const int s = c * 64 + i;
    const size_t row = (size_t)b * 2048 + s;
    const int ch0 = h * 256 + g * 64;
    const int cloc = g * 64;
    float y[64];
#pragma unroll
    for (int m = 0; m < 8; ++m) {
        const int cm = ch0 + m * 8;
        uint4 x3 = *(const uint4*)&pre[row * 1024 + cm];
        uint4 x2 = (s >= 1) ? *(const uint4*)&pre[(row - 1) * 1024 + cm] : make_uint4(0, 0, 0, 0);
        uint4 x1 = (s >= 2) ? *(const uint4*)&pre[(row - 2) * 1024 + cm] : make_uint4(0, 0, 0, 0);
        uint4 x0 = (s >= 3) ? *(const uint4*)&pre[(row - 3) * 1024 + cm] : make_uint4(0, 0, 0, 0);
        u32t c0[4] = {x0.x, x0.y, x0.z, x0.w};
        u32t c1[4] = {x1.x, x1.y, x1.z, x1.w};
        u32t c2[4] = {x2.x, x2.y, x2.z, x2.w};
        u32t c3[4] = {x3.x, x3.y, x3.z, x3.w};
#pragma unroll
        for (int p = 0; p < 4; ++p) {
            const int ch = m * 8 + p * 2;
            float4 wA = *(const float4*)&w[(size_t)(ch0 + ch) * 4];
            float4 wB = *(const float4*)&w[(size_t)(ch0 + ch + 1) * 4];
            float ya = wA.x * lo_bf(c0[p]) + wA.y * lo_bf(c1[p]) + wA.z * lo_bf(c2[p]) + wA.w * lo_bf(c3[p]);
            float yb = wB.x * hi_bf(c0[p]) + wB.y * hi_bf(c1[p]) + wB.z * hi_bf(c2[p]) + wB.w * hi_bf(c3[p]);
            ya = ya / (1.f + expf(-ya));
            yb = yb / (1.f + expf(-yb));
            y[ch] = ya; y[ch + 1] = yb;
        }
    }
    float ss = 0.f;
#pragma unroll
    for (int e = 0; e < 64; ++e) ss += y[e] * y[e];
    ss += __shfl_xor(ss, 1);
    ss += __shfl_xor(ss, 2);
    const float sc = rsqrtf(ss + 1e-6f);
#pragma unroll
    for (int m = 0; m < 8; ++m) {
        uint4 o;
        u32t* op = (u32t*)&o;
#pragma unroll
        for (int p = 0; p < 4; ++p) {
            u16t a = f2bf(y[m * 8 + p * 2] * sc);
            u16t bb2 = f2bf(y[m * 8 + p * 2 + 1] * sc);
            op[p] = (u32t)a | ((u32t)bb2 << 16);
        }
        *(uint4*)&rowout[row * 1024 + ch0 + m * 8] = o;
    }
#pragma unroll
    for (int e = 0; e < 64; ++e)
        trout[((size_t)bh * 256 + cloc + e) * 2048 + s] = f2bf(y[e] * sc);
}

// ====== prep: per 64-chunk T=(I+strict_lower(diag(b)KK^T))^-1 (hi/lo) =====
__global__ __launch_bounds__(256) void prep_kernel(const u16t* __restrict__ qcb,
                                                   const u16t* __restrict__ kcb,
                                                   const float* __restrict__ beta,
                                                   u16t* __restrict__ Tghi,
                                                   u16t* __restrict__ Tglo,
                                                   u16t* __restrict__ Agb) {
    __shared__ float KT[256][68];
    __shared__ float QT[256][68];
    __shared__ float Af[64][68];
    const int t = threadIdx.x;
    const int bhc = blockIdx.x;
    const int bh = bhc >> 5, c = bhc & 31;
    const int b = bh >> 2, h = bh & 3;
    const int tb = b * SS + c * CH;

    {
        const int i = t & 63, rb = t >> 6;
        const u16t* kg = kcb + (size_t)(tb + i) * HIDD + h * 256 + rb * 64;
        const u16t* qg = qcb + (size_t)(tb + i) * HIDD + h * 256 + rb * 64;
#pragma unroll
        for (int m = 0; m < 8; ++m) {
            uint4 kv = ((const uint4*)kg)[m];
            uint4 qv = ((const uint4*)qg)[m];
            u32t kw[4] = {kv.x, kv.y, kv.z, kv.w};
            u32t qw[4] = {qv.x, qv.y, qv.z, qv.w};
#pragma unroll
            for (int n = 0; n < 4; ++n) {
                int rr = rb * 64 + m * 8 + n * 2;
                KT[rr][i]     = lo_bf(kw[n]);
                KT[rr + 1][i] = hi_bf(kw[n]);
                QT[rr][i]     = lo_bf(qw[n]);
                QT[rr + 1][i] = hi_bf(qw[n]);
            }
        }
    }
    __syncthreads();

    const int it = t & 63, jb = t >> 6;
    float kk[16], qk[16];
#pragma unroll
    for (int m = 0; m < 16; ++m) { kk[m] = 0.f; qk[m] = 0.f; }
#pragma unroll 2
    for (int r = 0; r < 256; ++r) {
        float ki = KT[r][it];
        float qi = QT[r][it];
        float4 ka = *(const float4*)&KT[r][jb * 16 + 0];
        float4 kb = *(const float4*)&KT[r][jb * 16 + 4];
        float4 kc = *(const float4*)&KT[r][jb * 16 + 8];
        float4 kd = *(const float4*)&KT[r][jb * 16 + 12];
        float kj[16] = {ka.x, ka.y, ka.z, ka.w, kb.x, kb.y, kb.z, kb.w,
                        kc.x, kc.y, kc.z, kc.w, kd.x, kd.y, kd.z, kd.w};
#pragma unroll
        for (int m = 0; m < 16; ++m) { kk[m] += ki * kj[m]; qk[m] += qi * kj[m]; }
    }

    const float bta = beta[(size_t)(tb + it) * 4 + h];
    u16t* ag = Agb + (size_t)bhc * 4096 + (size_t)it * 64 + jb * 16;
#pragma unroll
    for (int m = 0; m < 16; ++m) {
        int j = jb * 16 + m;
        Af[it][j] = (j < it) ? bta * kk[m] : 0.f;
    }
#pragma unroll
    for (int m4 = 0; m4 < 4; ++m4) {
        ushort4 o;
        o.x = f2bf((jb * 16 + m4 * 4 + 0 <= it) ? qk[m4 * 4 + 0] : 0.f);
        o.y = f2bf((jb * 16 + m4 * 4 + 1 <= it) ? qk[m4 * 4 + 1] : 0.f);
        o.z = f2bf((jb * 16 + m4 * 4 + 2 <= it) ? qk[m4 * 4 + 2] : 0.f);
        o.w = f2bf((jb * 16 + m4 * 4 + 3 <= it) ? qk[m4 * 4 + 3] : 0.f);
        *(ushort4*)&ag[m4 * 4] = o;
    }
    __syncthreads();

    if (t < 64) {
        const int ccol = t;
        float tc[64];
#pragma unroll
        for (int j = 0; j < 64; ++j) tc[j] = (j == ccol) ? 1.f : 0.f;
#pragma unroll
        for (int i = 1; i < 64; ++i) {
            float a = 0.f;
#pragma unroll
            for (int j = 0; j < i; ++j) a += Af[i][j] * tc[j];
            tc[i] -= a;
        }
        u16t* th = Tghi + (size_t)bhc * 4096;
        u16t* tl = Tglo + (size_t)bhc * 4096;
#pragma unroll
        for (int i = 0; i < 64; ++i) {
            u16t hi = f2bf(tc[i]);
            th[i * 64 + ccol] = hi;
            tl[i * 64 + ccol] = f2bf(tc[i] - bf2f(hi));
        }
    }
}

// ====== prep2: per 128-macro-chunk compose T21 = -T22*G21*T11, A21 ========
__global__ __launch_bounds__(256) void prep2_kernel(const u16t* __restrict__ qcb,
                                                    const u16t* __restrict__ kcb,
                                                    const float* __restrict__ beta,
                                                    const u16t* __restrict__ Tghi,
                                                    const u16t* __restrict__ Tglo,
                                                    u16t* __restrict__ T21hi,
                                                    u16t* __restrict__ T21lo,
                                                    u16t* __restrict__ A21g) {
    __shared__ float Gs[64][68];
    __shared__ float T11f[64][68];
    __shared__ float T22f[64][68];
    __shared__ float Pf[64][68];

    const int t = threadIdx.x, l = t & 63, w = t >> 6;
    const int bhmc = blockIdx.x;
    const int bh = bhmc >> 4, mc = bhmc & 15;
    const int b = bh >> 2, h = bh & 3;
    const int t1 = b * SS + mc * 128;
    const int t2 = t1 + 64;
    const int vlow = l & 15, g4 = l >> 4;

    bf16x8 k2f[8], q2f[8];
    {
        const size_t rb = (size_t)(t2 + 16 * w + vlow) * 1024 + h * 256 + g4 * 8;
#pragma unroll
        for (int ks = 0; ks < 8; ++ks) {
            k2f[ks] = *(const bf16x8*)(kcb + rb + ks * 32);
            q2f[ks] = *(const bf16x8*)(qcb + rb + ks * 32);
        }
    }
    float bta2[4];
#pragma unroll
    for (int rg = 0; rg < 4; ++rg)
        bta2[rg] = beta[(size_t)(t2 + 16 * w + 4 * g4 + rg) * 4 + h];

#pragma unroll
    for (int jt = 0; jt < 4; ++jt) {
        bf16x8 k1f[8];
        const size_t rb1 = (size_t)(t1 + 16 * jt + vlow) * 1024 + h * 256 + g4 * 8;
#pragma unroll
        for (int ks = 0; ks < 8; ++ks)
            k1f[ks] = *(const bf16x8*)(kcb + rb1 + ks * 32);
        f32x4 Gacc = (f32x4){0.f, 0.f, 0.f, 0.f};
        f32x4 Aacc = (f32x4){0.f, 0.f, 0.f, 0.f};
#pragma unroll
        for (int ks = 0; ks < 8; ++ks) {
            Gacc = MFMA(k2f[ks], k1f[ks], Gacc);
            Aacc = MFMA(q2f[ks], k1f[ks], Aacc);
        }
        const int j = 16 * jt + vlow;
#pragma unroll
        for (int rg = 0; rg < 4; ++rg) {
            const int i = 16 * w + 4 * g4 + rg;
            Gs[i][j] = bta2[rg] * Gacc[rg];
            A21g[(size_t)bhmc * 4096 + (size_t)i * 64 + j] = f2bf(Aacc[rg]);
        }
    }
    {
        const size_t b11 = (size_t)(bh * 32 + 2 * mc) * 4096;
        const size_t b22 = (size_t)(bh * 32 + 2 * mc + 1) * 4096;
        for (int idx = t; idx < 4096; idx += 256) {
            const int i = idx >> 6, j = idx & 63;
            T11f[i][j] = bf2f(Tghi[b11 + idx]) + bf2f(Tglo[b11 + idx]);
            T22f[i][j] = bf2f(Tghi[b22 + idx]) + bf2f(Tglo[b22 + idx]);
        }
    }
    __syncthreads();

    {
        const int col = t & 63, rq = t >> 6;
        for (int ii = 0; ii < 16; ++ii) {
            const int i = rq * 16 + ii;
            float a = 0.f;
#pragma unroll 8
            for (int j = 0; j < 64; ++j) a += Gs[i][j] * T11f[j][col];
            Pf[i][col] = a;
        }
    }
    __syncthreads();

    {
        const int col = t & 63, rq = t >> 6;
        for (int ii = 0; ii < 16; ++ii) {
            const int i = rq * 16 + ii;
            float a = 0.f;
#pragma unroll 8
            for (int j = 0; j < 64; ++j) a += T22f[i][j] * Pf[j][col];
            a = -a;
            const u16t hi = f2bf(a);
            T21hi[(size_t)bhmc * 4096 + (size_t)i * 64 + col] = hi;
            T21lo[(size_t)bhmc * 4096 + (size_t)i * 64 + col] = f2bf(a - bf2f(hi));
        }
    }
}

// ====== MFMA scan v11: macro-chunks, 8 waves, 256-VGPR budget, lean regs ===
__global__ __launch_bounds__(512, 2) void scan_mfma(const u16t* __restrict__ qcb,
                                                    const u16t* __restrict__ kcb,
                                                    const u16t* __restrict__ ktr,
                                                    const u16t* __restrict__ vcb,
                                                    const float* __restrict__ beta,
                                                    const u16t* __restrict__ TghiG,
                                                    const u16t* __restrict__ TgloG,
                                                    const u16t* __restrict__ AgbG,
                                                    const u16t* __restrict__ T21hi,
                                                    const u16t* __restrict__ T21lo,
                                                    const u16t* __restrict__ A21g,
                                                    u16t* __restrict__ o_raw) {
    __shared__ u16t Shi[16 * 256];
    __shared__ u16t Slo[16 * 256];
    __shared__ u16t Rhi[16 * 128];
    __shared__ u16t Rlo[16 * 128];
    __shared__ u16t Uhi[16 * 128];
    __shared__ u16t Ulo[16 * 128];

    const int t = threadIdx.x, l = t & 63, w = t >> 6;   // w: 0..7 = t-tile
    const int bh = blockIdx.x & 7, vt = blockIdx.x >> 3;
    const int b = bh >> 2, h = bh & 3;
    const int vcol0 = vt * 16;
    const int vlow = l & 15, g4 = l >> 4;
    const int sw = vlow & 7;
    const bool isHi = (w >= 4);
    const int w4 = isHi ? (w - 4) : w;

    for (int i = t; i < 16 * 256; i += 512) { Shi[i] = 0; Slo[i] = 0; }
    f32x4 sf[2];
    sf[0] = (f32x4){0.f, 0.f, 0.f, 0.f};
    sf[1] = (f32x4){0.f, 0.f, 0.f, 0.f};

    bf16x8 kf[8], qf[8], tfh[4], tfl[4];
    u16t vfb[4];
    float bta[4];

    auto loadKQ = [&](int c) {
        const size_t rb = (size_t)(b * 2048 + c * 128 + 16 * w + vlow) * 1024 + h * 256 + g4 * 8;
#pragma unroll
        for (int ks = 0; ks < 8; ++ks) {
            kf[ks] = *(const bf16x8*)(kcb + rb + ks * 32);
            qf[ks] = *(const bf16x8*)(qcb + rb + ks * 32);
        }
    };
    auto loadVB = [&](int c) {
        const int r0 = b * 2048 + c * 128 + 16 * w + 4 * g4;
#pragma unroll
        for (int rg = 0; rg < 4; ++rg) {
            vfb[rg] = vcb[(size_t)(r0 + rg) * 1024 + h * 256 + vcol0 + vlow];
            bta[rg] = beta[(size_t)(r0 + rg) * 4 + h];
        }
    };
    auto loadT = [&](int c) {
        if (!isHi) {
            const size_t bs = (size_t)(bh * 32 + 2 * c) * 4096 + (size_t)(16 * w + vlow) * 64 + g4 * 8;
            tfh[0] = *(const bf16x8*)(TghiG + bs);
            tfh[1] = *(const bf16x8*)(TghiG + bs + 32);
            tfl[0] = *(const bf16x8*)(TgloG + bs);
            tfl[1] = *(const bf16x8*)(TgloG + bs + 32);
        } else {
            const size_t b21 = (size_t)(bh * 16 + c) * 4096 + (size_t)(16 * w4 + vlow) * 64 + g4 * 8;
            tfh[0] = *(const bf16x8*)(T21hi + b21);
            tfh[1] = *(const bf16x8*)(T21hi + b21 + 32);
            tfl[0] = *(const bf16x8*)(T21lo + b21);
            tfl[1] = *(const bf16x8*)(T21lo + b21 + 32);
            const size_t b22 = (size_t)(bh * 32 + 2 * c + 1) * 4096 + (size_t)(16 * w4 + vlow) * 64 + g4 * 8;
            tfh[2] = *(const bf16x8*)(TghiG + b22);
            tfh[3] = *(const bf16x8*)(TghiG + b22 + 32);
            tfl[2] = *(const bf16x8*)(TgloG + b22);
            tfl[3] = *(const bf16x8*)(TgloG + b22 + 32);
        }
    };

    loadKQ(0); loadVB(0); loadT(0);
    __syncthreads();

    for (int c = 0; c < NMC; ++c) {
        const int cn = (c + 1 < NMC) ? c + 1 : c;
        const int trow0 = b * 2048 + c * 128;

        // ---- phase A: W = K*(Shi+Slo); O1 = Q*(Shi+Slo) ----
        f32x4 Wacc = (f32x4){0.f, 0.f, 0.f, 0.f};
        f32x4 O1   = (f32x4){0.f, 0.f, 0.f, 0.f};
#pragma unroll
        for (int ks = 0; ks < 8; ++ks) {
            const int pb = (((ks * 4 + g4) ^ sw) << 3);
            bf16x8 bH = *(const bf16x8*)&Shi[vlow * 256 + pb];
            bf16x8 bL = *(const bf16x8*)&Slo[vlow * 256 + pb];
            Wacc = MFMA(kf[ks], bH, Wacc); Wacc = MFMA(kf[ks], bL, Wacc);
            O1   = MFMA(qf[ks], bH, O1);   O1   = MFMA(qf[ks], bL, O1);
        }
        // R = beta*(V - W) -> LDS hi/lo
        {
            const int tslot = 2 * w + (g4 >> 1);
            const int base = vlow * 128 + ((tslot ^ sw) << 3) + ((g4 & 1) << 2);
            u16t rh[4], rl[4];
#pragma unroll
            for (int rg = 0; rg < 4; ++rg) {
                float rv = bta[rg] * (bf2f(vfb[rg]) - Wacc[rg]);
                rh[rg] = f2bf(rv);
                rl[rg] = f2bf(rv - bf2f(rh[rg]));
            }
            uint2 ph, pl;
            ph.x = (u32t)rh[0] | ((u32t)rh[1] << 16); ph.y = (u32t)rh[2] | ((u32t)rh[3] << 16);
            pl.x = (u32t)rl[0] | ((u32t)rl[1] << 16); pl.y = (u32t)rl[2] | ((u32t)rl[3] << 16);
            *(uint2*)&Rhi[base] = ph;
            *(uint2*)&Rlo[base] = pl;
        }
        loadKQ(cn);
        loadVB(cn);
        __syncthreads();

        // ---- phase B: U = T128 * R (static unrolled per branch) ----
        f32x4 Uacc = (f32x4){0.f, 0.f, 0.f, 0.f};
        if (isHi) {
#pragma unroll
            for (int ks = 0; ks < 4; ++ks) {
                const int pb = (((ks * 4 + g4) ^ sw) << 3);
                bf16x8 bH = *(const bf16x8*)&Rhi[vlow * 128 + pb];
                bf16x8 bL = *(const bf16x8*)&Rlo[vlow * 128 + pb];
                Uacc = MFMA(tfh[ks], bH, Uacc);
                Uacc = MFMA(tfh[ks], bL, Uacc);
                Uacc = MFMA(tfl[ks], bH, Uacc);
            }
        } else {
#pragma unroll
            for (int ks = 0; ks < 2; ++ks) {
                const int pb = (((ks * 4 + g4) ^ sw) << 3);
                bf16x8 bH = *(const bf16x8*)&Rhi[vlow * 128 + pb];
                bf16x8 bL = *(const bf16x8*)&Rlo[vlow * 128 + pb];
                Uacc = MFMA(tfh[ks], bH, Uacc);
                Uacc = MFMA(tfh[ks], bL, Uacc);
                Uacc = MFMA(tfl[ks], bH, Uacc);
            }
        }
        {
            const int tslot = 2 * w + (g4 >> 1);
            const int base = vlow * 128 + ((tslot ^ sw) << 3) + ((g4 & 1) << 2);
            u16t uh[4], ul[4];
#pragma unroll
            for (int rg = 0; rg < 4; ++rg) {
                uh[rg] = f2bf(Uacc[rg]);
                ul[rg] = f2bf(Uacc[rg] - bf2f(uh[rg]));
            }
            uint2 ph, pl;
            ph.x = (u32t)uh[0] | ((u32t)uh[1] << 16); ph.y = (u32t)uh[2] | ((u32t)uh[3] << 16);
            pl.x = (u32t)ul[0] | ((u32t)ul[1] << 16); pl.y = (u32t)ul[2] | ((u32t)ul[3] << 16);
            *(uint2*)&Uhi[base] = ph;
            *(uint2*)&Ulo[base] = pl;
        }
        loadT(cn);
        __syncthreads();

        // ---- phase C: O = O1 + A128*U ; S += K^T*U (A/KC loaded at use) ----
        bf16x8 uhf[4], ulf[4];
#pragma unroll
        for (int ks = 0; ks < 4; ++ks) {
            const int pb = (((ks * 4 + g4) ^ sw) << 3);
            uhf[ks] = *(const bf16x8*)&Uhi[vlow * 128 + pb];
            ulf[ks] = *(const bf16x8*)&Ulo[vlow * 128 + pb];
        }
        f32x4 Oacc = O1;
        if (isHi) {
            const size_t b21 = (size_t)(bh * 16 + c) * 4096 + (size_t)(16 * w4 + vlow) * 64 + g4 * 8;
            bf16x8 a0 = *(const bf16x8*)(A21g + b21);
            bf16x8 a1 = *(const bf16x8*)(A21g + b21 + 32);
            const size_t b22 = (size_t)(bh * 32 + 2 * c + 1) * 4096 + (size_t)(16 * w4 + vlow) * 64 + g4 * 8;
            bf16x8 a2 = *(const bf16x8*)(AgbG + b22);
            bf16x8 a3 = *(const bf16x8*)(AgbG + b22 + 32);
            Oacc = MFMA(a0, uhf[0], Oacc); Oacc = MFMA(a0, ulf[0], Oacc);
            Oacc = MFMA(a1, uhf[1], Oacc); Oacc = MFMA(a1, ulf[1], Oacc);
            Oacc = MFMA(a2, uhf[2], Oacc); Oacc = MFMA(a2, ulf[2], Oacc);
            Oacc = MFMA(a3, uhf[3], Oacc); Oacc = MFMA(a3, ulf[3], Oacc);
        } else {
            const size_t bs = (size_t)(bh * 32 + 2 * c) * 4096 + (size_t)(16 * w + vlow) * 64 + g4 * 8;
            bf16x8 a0 = *(const bf16x8*)(AgbG + bs);
            bf16x8 a1 = *(const bf16x8*)(AgbG + bs + 32);
            Oacc = MFMA(a0, uhf[0], Oacc); Oacc = MFMA(a0, ulf[0], Oacc);
            Oacc = MFMA(a1, uhf[1], Oacc); Oacc = MFMA(a1, ulf[1], Oacc);
        }
#pragma unroll
        for (int rg = 0; rg < 4; ++rg)
            o_raw[(size_t)(trow0 + 16 * w + 4 * g4 + rg) * 1024 + h * 256 + vcol0 + vlow] = f2bf(Oacc[rg]);

#pragma unroll
        for (int q2 = 0; q2 < 2; ++q2) {
            const size_t cb2 = ((size_t)bh * 256 + 32 * w + 16 * q2 + vlow) * 2048 + c * 128 + g4 * 8;
            bf16x8 k0 = *(const bf16x8*)(ktr + cb2);
            bf16x8 k1 = *(const bf16x8*)(ktr + cb2 + 32);
            bf16x8 k2 = *(const bf16x8*)(ktr + cb2 + 64);
            bf16x8 k3 = *(const bf16x8*)(ktr + cb2 + 96);
            sf[q2] = MFMA(k0, uhf[0], sf[q2]); sf[q2] = MFMA(k0, ulf[0], sf[q2]);
            sf[q2] = MFMA(k1, uhf[1], sf[q2]); sf[q2] = MFMA(k1, ulf[1], sf[q2]);
            sf[q2] = MFMA(k2, uhf[2], sf[q2]); sf[q2] = MFMA(k2, ulf[2], sf[q2]);
            sf[q2] = MFMA(k3, uhf[3], sf[q2]); sf[q2] = MFMA(k3, ulf[3], sf[q2]);
        }

        // S mirror refresh (hi/lo)
#pragma unroll
        for (int q2 = 0; q2 < 2; ++q2) {
            u16t sh[4], sl[4];
#pragma unroll
            for (int rg = 0; rg < 4; ++rg) {
                u16t hi = f2bf(sf[q2][rg]);
                sh[rg] = hi;
                sl[rg] = f2bf(sf[q2][rg] - bf2f(hi));
            }
            const int rslot = 4 * w + 2 * q2 + (g4 >> 1);
            const int base = vlow * 256 + ((rslot ^ sw) << 3) + ((g4 & 1) << 2);
            uint2 ph, pl;
            ph.x = (u32t)sh[0] | ((u32t)sh[1] << 16); ph.y = (u32t)sh[2] | ((u32t)sh[3] << 16);
            pl.x = (u32t)sl[0] | ((u32t)sl[1] << 16); pl.y = (u32t)sl[2] | ((u32t)sl[3] << 16);
            *(uint2*)&Shi[base] = ph;
            *(uint2*)&Slo[base] = pl;
        }
        __syncthreads();
    }
}

// =================== rms_norm (bf16 in -> bf16 out) ======================
__global__ __launch_bounds__(256) void rms_kernel(const u16t* __restrict__ in,
                                                  const float* __restrict__ w,
                                                  u16t* __restrict__ out) {
    const int gw   = (blockIdx.x * blockDim.x + threadIdx.x) >> 6;
    const int lane = threadIdx.x & 63;
    const int r = gw >> 2;
    const int h = gw & 3;
    const size_t base = (size_t)r * HIDD + h * 256 + lane * 4;
    ushort4 xv = *(const ushort4*)&in[base];
    float x0 = bf2f(xv.x), x1 = bf2f(xv.y), x2 = bf2f(xv.z), x3 = bf2f(xv.w);
    float ss = x0 * x0 + x1 * x1 + x2 * x2 + x3 * x3;
    ss = waveReduceSum(ss);
    const float sc = rsqrtf(ss * (1.0f / 256.0f) + 1e-5f);
    float4 wv = *(const float4*)&w[lane * 4];
    ushort4 o;
    o.x = f2bf(x0 * sc * wv.x); o.y = f2bf(x1 * sc * wv.y);
    o.z = f2bf(x2 * sc * wv.z); o.w = f2bf(x3 * sc * wv.w);
    *(ushort4*)&out[base] = o;
}

extern "C" void kernel_launch(void* const* d_in, const int* in_sizes, int n_in,
                              void* d_out, int out_size, void* d_ws, size_t ws_size,
                              hipStream_t stream) {
    const float* X      = (const float*)d_in[0];
    const float* Wq     = (const float*)d_in[1];
    const float* Wk     = (const float*)d_in[2];
    const float* Wv     = (const float*)d_in[3];
    const float* Wb     = (const float*)d_in[4];
    const float* conv_q = (const float*)d_in[5];
    const float* conv_k = (const float*)d_in[6];
    const float* conv_v = (const float*)d_in[7];
    const float* norm_w = (const float*)d_in[8];
    const float* Wo     = (const float*)d_in[9];
    float* out = (float*)d_out;

    char* W8 = (char*)d_ws;
    const size_t MB = 1u << 20;
    u16t* Xbf   = (u16t*)(W8 + 0 * MB);
    u16t* o_raw = Xbf;
    u16t* qpre  = (u16t*)(W8 + 8 * MB);
    u16t* T21hi = (u16t*)(W8 + 8 * MB);
    u16t* T21lo = (u16t*)(W8 + 10 * MB);
    u16t* A21g  = (u16t*)(W8 + 12 * MB);
    u16t* o_nrm = qpre;
    u16t* kpre  = (u16t*)(W8 + 16 * MB);
    u16t* Tghi  = (u16t*)(W8 + 16 * MB);
    u16t* Tglo  = (u16t*)(W8 + 18 * MB);
    u16t* Agb   = (u16t*)(W8 + 20 * MB);
    u16t* vpre  = (u16t*)(W8 + 24 * MB);
    u16t* ktr   = (u16t*)(W8 + 24 * MB);
    u16t* WqT   = (u16t*)(W8 + 32 * MB);
    u16t* qcb   = (u16t*)(W8 + 32 * MB);
    u16t* WkT   = (u16t*)(W8 + 40 * MB);
    u16t* kcb   = (u16t*)(W8 + 40 * MB);
    u16t* WvT   = (u16t*)(W8 + 48 * MB);
    u16t* vcb   = (u16t*)(W8 + 48 * MB);
    u16t* WoT   = (u16t*)(W8 + 56 * MB);
    float* betab = (float*)(W8 + 58 * MB);

    const size_t PL = 4194304;   // 8 MB plane stride in u16 elements

    f2bf_kernel<<<2048, 256, 0, stream>>>(X, Xbf);
    transpose_w4<<<dim3(16, 16, 4), 256, 0, stream>>>(Wq, Wk, Wv, Wo, WqT, WkT, WvT, WoT);

    gemm_mfma<<<dim3(24, 32), 256, 0, stream>>>(Xbf, WqT, nullptr, qpre, 1,
                                                ROWS, 3072, HIDD, PL, PL, 2);
    beta_kernel<<<ROWS / 4, 256, 0, stream>>>(X, Wb, betab);

    conv_qv<<<dim3(ROWS, 2), 256, 0, stream>>>(qpre, conv_q, qcb, vpre, conv_v, vcb);
    conv_k_chunk<<<256, 256, 0, stream>>>(kpre, conv_k, kcb, ktr);

    prep_kernel<<<256, 256, 0, stream>>>(qcb, kcb, betab, Tghi, Tglo, Agb);
    prep2_kernel<<<128, 256, 0, stream>>>(qcb, kcb, betab, Tghi, Tglo, T21hi, T21lo, A21g);
    scan_mfma<<<128, 512, 0, stream>>>(qcb, kcb, ktr, vcb, betab, Tghi, Tglo, Agb,
                                       T21hi, T21lo, A21g, o_raw);

    rms_kernel<<<ROWS, 256, 0, stream>>>(o_raw, norm_w, o_nrm);
    gemm_mfma<<<dim3(8, 32), 256, 0, stream>>>(o_nrm, WoT, out, nullptr, 0,
                                               ROWS, HIDD, HIDD, 0, 0, 1);
}

// Round 15
// 282.544 us; speedup vs baseline: 3.9782x; 1.2095x over previous
//
#include <hip/hip_runtime.h>
#include <math.h>

#define BB   2
#define SS   2048
#define HIDD 1024
#define ROWS 4096
#define NCH  32
#define CH   64

typedef unsigned short u16t;
typedef unsigned int   u32t;

typedef __attribute__((ext_vector_type(8))) short bf16x8;
typedef __attribute__((ext_vector_type(4))) float f32x4;

__device__ __forceinline__ float bf2f(u16t u) { return __uint_as_float(((u32t)u) << 16); }
__device__ __forceinline__ u16t f2bf(float f) {
    u32t b = __float_as_uint(f);
    return (u16t)((b + 0x7FFFu + ((b >> 16) & 1u)) >> 16);
}
__device__ __forceinline__ float lo_bf(u32t u) { return __uint_as_float(u << 16); }
__device__ __forceinline__ float hi_bf(u32t u) { return __uint_as_float(u & 0xFFFF0000u); }

__device__ __forceinline__ float waveReduceSum(float v) {
#pragma unroll
    for (int m = 1; m < 64; m <<= 1) v += __shfl_xor(v, m, 64);
    return v;
}

__device__ __forceinline__ void gload16(const void* g, void* l) {
    __builtin_amdgcn_global_load_lds(
        (const __attribute__((address_space(1))) unsigned int*)g,
        (__attribute__((address_space(3))) unsigned int*)l, 16, 0, 0);
}

#define MFMA(a, b, c) __builtin_amdgcn_mfma_f32_16x16x32_bf16(a, b, c, 0, 0, 0)

// ==== fused prep: z 0..3 = W transpose->bf16; z 4..11 = X f32->bf16 =====
__global__ __launch_bounds__(256) void pre_kernel(const float* __restrict__ X,
                                                  u16t* __restrict__ Xbf,
                                                  const float* __restrict__ W0,
                                                  const float* __restrict__ W1,
                                                  const float* __restrict__ W2,
                                                  const float* __restrict__ W3,
                                                  u16t* __restrict__ T0,
                                                  u16t* __restrict__ T1,
                                                  u16t* __restrict__ T2,
                                                  u16t* __restrict__ T3) {
    const int z = blockIdx.z;
    const int t = threadIdx.x;
    if (z >= 4) {
        const int blk = (z - 4) * 256 + blockIdx.y * 16 + blockIdx.x;  // 0..2047
        const size_t idx = ((size_t)blk * 256 + t) * 8;
        float4 a = *(const float4*)&X[idx];
        float4 b = *(const float4*)&X[idx + 4];
        ushort4 o1, o2;
        o1.x = f2bf(a.x); o1.y = f2bf(a.y); o1.z = f2bf(a.z); o1.w = f2bf(a.w);
        o2.x = f2bf(b.x); o2.y = f2bf(b.y); o2.z = f2bf(b.z); o2.w = f2bf(b.w);
        *(ushort4*)&Xbf[idx] = o1;
        *(ushort4*)&Xbf[idx + 4] = o2;
        return;
    }
    __shared__ u16t tile[64][65];
    const float* W = (z == 0) ? W0 : (z == 1) ? W1 : (z == 2) ? W2 : W3;
    u16t* WT = (z == 0) ? T0 : (z == 1) ? T1 : (z == 2) ? T2 : T3;
    const int r0 = blockIdx.y * 64, c0 = blockIdx.x * 64;
    const int lr = t >> 2, lc4 = (t & 3) * 16;
#pragma unroll
    for (int m = 0; m < 4; ++m) {
        float4 v = *(const float4*)&W[(size_t)(r0 + lr) * 1024 + c0 + lc4 + m * 4];
        tile[lr][lc4 + m * 4 + 0] = f2bf(v.x);
        tile[lr][lc4 + m * 4 + 1] = f2bf(v.y);
        tile[lr][lc4 + m * 4 + 2] = f2bf(v.z);
        tile[lr][lc4 + m * 4 + 3] = f2bf(v.w);
    }
    __syncthreads();
#pragma unroll
    for (int m = 0; m < 16; ++m)
        WT[(size_t)(c0 + lr) * 1024 + r0 + lc4 + m] = tile[lc4 + m][lr];
}

// ======= MFMA GEMM: C[M,N] = A[M,K] * BT[N,K]^T, plane-strided B/C =======
// XCD-chunked swizzle: linear block id -> contiguous (W x H) region per XCD.
__global__ __launch_bounds__(256) void gemm_mfma(const u16t* __restrict__ A,
                                                 const u16t* __restrict__ BT,
                                                 float* __restrict__ Cf,
                                                 u16t* __restrict__ Cb, int obf,
                                                 int M, int N, int K,
                                                 size_t bStrideP, size_t cStrideP,
                                                 int CX) {
    __shared__ u16t As[128 * 64];
    __shared__ u16t Bs[128 * 64];
    const int t = threadIdx.x, l = t & 63, w = t >> 6;
    const int wr = w >> 1, wc = w & 1;

    const int lin = blockIdx.y * gridDim.x + blockIdx.x;
    const int xcd = lin & 7, idx = lin >> 3;
    const int Wc = gridDim.x / CX;
    const int Hc = (gridDim.y * CX) >> 3;
    const int colB = (xcd % CX) * Wc + idx % Wc;
    const int rowB = (xcd / CX) * Hc + idx / Wc;

    const int rowBase = rowB * 128, colBase = colB * 128;
    const int l15 = l & 15, g4 = l >> 4;

    const int bplane = colBase >> 10;
    const int bcol = colBase & 1023;

    const int srow = l >> 3;
    const int sj = (l & 7) ^ srow;
    const u16t* aSrc = A + (size_t)(rowBase + srow) * K + sj * 8;
    const u16t* bSrc = BT + (size_t)bplane * bStrideP + (size_t)(bcol + srow) * K + sj * 8;

    f32x4 acc[4][4];
#pragma unroll
    for (int i = 0; i < 4; ++i)
#pragma unroll
        for (int j = 0; j < 4; ++j) acc[i][j] = (f32x4){0.f, 0.f, 0.f, 0.f};

    for (int k0 = 0; k0 < K; k0 += 64) {
#pragma unroll
        for (int i = 0; i < 4; ++i) {
            const int rb = (i * 4 + w) * 8;
            gload16(aSrc + (size_t)rb * K + k0, &As[rb * 64]);
            gload16(bSrc + (size_t)rb * K + k0, &Bs[rb * 64]);
        }
        __syncthreads();
#pragma unroll
        for (int kh = 0; kh < 2; ++kh) {
            bf16x8 aF[4], bF[4];
#pragma unroll
            for (int mi = 0; mi < 4; ++mi) {
                const int row = wr * 64 + mi * 16 + l15;
                const int phys = (kh * 4 + g4) ^ (row & 7);
                aF[mi] = *(const bf16x8*)&As[row * 64 + phys * 8];
            }
#pragma unroll
            for (int ni = 0; ni < 4; ++ni) {
                const int row = wc * 64 + ni * 16 + l15;
                const int phys = (kh * 4 + g4) ^ (row & 7);
                bF[ni] = *(const bf16x8*)&Bs[row * 64 + phys * 8];
            }
#pragma unroll
            for (int mi = 0; mi < 4; ++mi)
#pragma unroll
                for (int ni = 0; ni < 4; ++ni)
                    acc[mi][ni] = MFMA(aF[mi], bF[ni], acc[mi][ni]);
        }
        __syncthreads();
    }
#pragma unroll
    for (int mi = 0; mi < 4; ++mi)
#pragma unroll
        for (int ni = 0; ni < 4; ++ni)
#pragma unroll
            for (int rg = 0; rg < 4; ++rg) {
                const int row = rowBase + wr * 64 + mi * 16 + g4 * 4 + rg;
                const int col = colBase + wc * 64 + ni * 16 + l15;
                const int plane = col >> 10, cc = col & 1023;
                const float v = acc[mi][ni][rg];
                if (obf) Cb[(size_t)plane * cStrideP + (size_t)row * 1024 + cc] = f2bf(v);
                else     Cf[(size_t)plane * cStrideP + (size_t)row * 1024 + cc] = v;
            }
}

// == causal conv(K=4)+silu(+l2norm) q/v fused; blockIdx.y==2 => beta =======
__global__ __launch_bounds__(256) void conv_qvb(const u16t* __restrict__ inQ,
                                                const float* __restrict__ wQ,
                                                u16t* __restrict__ outQ,
                                                const u16t* __restrict__ inV,
                                                const float* __restrict__ wV,
                                                u16t* __restrict__ outV,
                                                const float* __restrict__ X,
                                                const float* __restrict__ Wb,
                                                float* __restrict__ beta) {
    if (blockIdx.y == 2) {
        if (blockIdx.x >= ROWS / 4) return;
        const int gw   = (blockIdx.x * blockDim.x + threadIdx.x) >> 6;
        const int lane = threadIdx.x & 63;
        const float* x = X + (size_t)gw * HIDD;
        float a0 = 0.f, a1 = 0.f, a2 = 0.f, a3 = 0.f;
#pragma unroll
        for (int i = 0; i < 4; ++i) {
            const int k = lane * 16 + i * 4;
            float4 xv = *(const float4*)&x[k];
            float4 w0 = *(const float4*)&Wb[(size_t)(k + 0) * 4];
            float4 w1 = *(const float4*)&Wb[(size_t)(k + 1) * 4];
            float4 w2 = *(const float4*)&Wb[(size_t)(k + 2) * 4];
            float4 w3 = *(const float4*)&Wb[(size_t)(k + 3) * 4];
            a0 += xv.x * w0.x + xv.y * w1.x + xv.z * w2.x + xv.w * w3.x;
            a1 += xv.x * w0.y + xv.y * w1.y + xv.z * w2.y + xv.w * w3.y;
            a2 += xv.x * w0.z + xv.y * w1.z + xv.z * w2.z + xv.w * w3.z;
            a3 += xv.x * w0.w + xv.y * w1.w + xv.z * w2.w + xv.w * w3.w;
        }
        a0 = waveReduceSum(a0); a1 = waveReduceSum(a1);
        a2 = waveReduceSum(a2); a3 = waveReduceSum(a3);
        if (lane == 0) {
            float4 o = make_float4(1.f / (1.f + expf(-a0)), 1.f / (1.f + expf(-a1)),
                                   1.f / (1.f + expf(-a2)), 1.f / (1.f + expf(-a3)));
            *(float4*)&beta[(size_t)gw * 4] = o;
        }
        return;
    }
    const int isQ = (blockIdx.y == 0);
    const u16t* in = isQ ? inQ : inV;
    const float* w = isQ ? wQ : wV;
    u16t* out      = isQ ? outQ : outV;
    const int doL2 = isQ;

    const int gw   = (blockIdx.x * blockDim.x + threadIdx.x) >> 6;
    const int lane = threadIdx.x & 63;
    const int r = gw >> 2;
    const int h = gw & 3;
    const int b = r >> 11;
    const int s = r & 2047;
    const int c4 = h * 256 + lane * 4;

    const float4 wr0 = *(const float4*)&w[(size_t)(c4 + 0) * 4];
    const float4 wr1 = *(const float4*)&w[(size_t)(c4 + 1) * 4];
    const float4 wr2 = *(const float4*)&w[(size_t)(c4 + 2) * 4];
    const float4 wr3 = *(const float4*)&w[(size_t)(c4 + 3) * 4];

    const size_t rowB = (size_t)(b << 11);
    float x0[4] = {0, 0, 0, 0}, x1[4] = {0, 0, 0, 0}, x2[4] = {0, 0, 0, 0}, x3[4];
    ushort4 u;
    if (s >= 3) { u = *(const ushort4*)&in[(rowB + s - 3) * HIDD + c4];
        x0[0] = bf2f(u.x); x0[1] = bf2f(u.y); x0[2] = bf2f(u.z); x0[3] = bf2f(u.w); }
    if (s >= 2) { u = *(const ushort4*)&in[(rowB + s - 2) * HIDD + c4];
        x1[0] = bf2f(u.x); x1[1] = bf2f(u.y); x1[2] = bf2f(u.z); x1[3] = bf2f(u.w); }
    if (s >= 1) { u = *(const ushort4*)&in[(rowB + s - 1) * HIDD + c4];
        x2[0] = bf2f(u.x); x2[1] = bf2f(u.y); x2[2] = bf2f(u.z); x2[3] = bf2f(u.w); }
    u = *(const ushort4*)&in[(rowB + s) * HIDD + c4];
    x3[0] = bf2f(u.x); x3[1] = bf2f(u.y); x3[2] = bf2f(u.z); x3[3] = bf2f(u.w);

    float y0 = wr0.x * x0[0] + wr0.y * x1[0] + wr0.z * x2[0] + wr0.w * x3[0];
    float y1 = wr1.x * x0[1] + wr1.y * x1[1] + wr1.z * x2[1] + wr1.w * x3[1];
    float y2 = wr2.x * x0[2] + wr2.y * x1[2] + wr2.z * x2[2] + wr2.w * x3[2];
    float y3 = wr3.x * x0[3] + wr3.y * x1[3] + wr3.z * x2[3] + wr3.w * x3[3];

    y0 = y0 / (1.f + expf(-y0)); y1 = y1 / (1.f + expf(-y1));
    y2 = y2 / (1.f + expf(-y2)); y3 = y3 / (1.f + expf(-y3));

    if (doL2) {
        float ss = y0 * y0 + y1 * y1 + y2 * y2 + y3 * y3;
        ss = waveReduceSum(ss);
        float sc = rsqrtf(ss + 1e-6f);
        y0 *= sc; y1 *= sc; y2 *= sc; y3 *= sc;
    }
    ushort4 o;
    o.x = f2bf(y0); o.y = f2bf(y1); o.z = f2bf(y2); o.w = f2bf(y3);
    *(ushort4*)&out[(size_t)r * HIDD + c4] = o;
}

// ====== conv for K: row-major out + transposed ktr[bh*256+r][t] ==========
__global__ __launch_bounds__(256) void conv_k_chunk(const u16t* __restrict__ pre,
                                                    const float* __restrict__ w,
                                                    u16t* __restrict__ rowout,
                                                    u16t* __restrict__ trout) {
    const int t = threadIdx.x;
    const int bh = blockIdx.x >> 5, c = blockIdx.x & 31;
    const int b = bh >> 2, h = bh & 3;
    const int i = t >> 2, g = t & 3;
    const int s = c * 64 + i;
    const size_t row = (size_t)b * 2048 + s;
    const int ch0 = h * 256 + g * 64;
    const int cloc = g * 64;
    float y[64];
#pragma unroll
    for (int m = 0; m < 8; ++m) {
        const int cm = ch0 + m * 8;
        uint4 x3 = *(const uint4*)&pre[row * 1024 + cm];
        uint4 x2 = (s >= 1) ? *(const uint4*)&pre[(row - 1) * 1024 + cm] : make_uint4(0, 0, 0, 0);
        uint4 x1 = (s >= 2) ? *(const uint4*)&pre[(row - 2) * 1024 + cm] : make_uint4(0, 0, 0, 0);
        uint4 x0 = (s >= 3) ? *(const uint4*)&pre[(row - 3) * 1024 + cm] : make_uint4(0, 0, 0, 0);
        u32t c0[4] = {x0.x, x0.y, x0.z, x0.w};
        u32t c1[4] = {x1.x, x1.y, x1.z, x1.w};
        u32t c2[4] = {x2.x, x2.y, x2.z, x2.w};
        u32t c3[4] = {x3.x, x3.y, x3.z, x3.w};
#pragma unroll
        for (int p = 0; p < 4; ++p) {
            const int ch = m * 8 + p * 2;
            float4 wA = *(const float4*)&w[(size_t)(ch0 + ch) * 4];
            float4 wB = *(const float4*)&w[(size_t)(ch0 + ch + 1) * 4];
            float ya = wA.x * lo_bf(c0[p]) + wA.y * lo_bf(c1[p]) + wA.z * lo_bf(c2[p]) + wA.w * lo_bf(c3[p]);
            float yb = wB.x * hi_bf(c0[p]) + wB.y * hi_bf(c1[p]) + wB.z * hi_bf(c2[p]) + wB.w * hi_bf(c3[p]);
            ya = ya / (1.f + expf(-ya));
            yb = yb / (1.f + expf(-yb));
            y[ch] = ya; y[ch + 1] = yb;
        }
    }
    float ss = 0.f;
#pragma unroll
    for (int e = 0; e < 64; ++e) ss += y[e] * y[e];
    ss += __shfl_xor(ss, 1);
    ss += __shfl_xor(ss, 2);
    const float sc = rsqrtf(ss + 1e-6f);
#pragma unroll
    for (int m = 0; m < 8; ++m) {
        uint4 o;
        u32t* op = (u32t*)&o;
#pragma unroll
        for (int p = 0; p < 4; ++p) {
            u16t a = f2bf(y[m * 8 + p * 2] * sc);
            u16t bb2 = f2bf(y[m * 8 + p * 2 + 1] * sc);
            op[p] = (u32t)a | ((u32t)bb2 << 16);
        }
        *(uint4*)&rowout[row * 1024 + ch0 + m * 8] = o;
    }
#pragma unroll
    for (int e = 0; e < 64; ++e)
        trout[((size_t)bh * 256 + cloc + e) * 2048 + s] = f2bf(y[e] * sc);
}

// ====== prep: per chunk T=(I+strict_lower(diag(b)KK^T))^-1 (bf16 hi/lo) ===
__global__ __launch_bounds__(256) void prep_kernel(const u16t* __restrict__ qcb,
                                                   const u16t* __restrict__ kcb,
                                                   const float* __restrict__ beta,
                                                   u16t* __restrict__ Tghi,
                                                   u16t* __restrict__ Tglo,
                                                   u16t* __restrict__ Agb) {
    __shared__ float KT[256][68];
    __shared__ float QT[256][68];
    __shared__ float Af[64][68];
    const int t = threadIdx.x;
    const int bhc = blockIdx.x;
    const int bh = bhc >> 5, c = bhc & 31;
    const int b = bh >> 2, h = bh & 3;
    const int tb = b * SS + c * CH;

    {
        const int i = t & 63, rb = t >> 6;
        const u16t* kg = kcb + (size_t)(tb + i) * HIDD + h * 256 + rb * 64;
        const u16t* qg = qcb + (size_t)(tb + i) * HIDD + h * 256 + rb * 64;
#pragma unroll
        for (int m = 0; m < 8; ++m) {
            uint4 kv = ((const uint4*)kg)[m];
            uint4 qv = ((const uint4*)qg)[m];
            u32t kw[4] = {kv.x, kv.y, kv.z, kv.w};
            u32t qw[4] = {qv.x, qv.y, qv.z, qv.w};
#pragma unroll
            for (int n = 0; n < 4; ++n) {
                int rr = rb * 64 + m * 8 + n * 2;
                KT[rr][i]     = lo_bf(kw[n]);
                KT[rr + 1][i] = hi_bf(kw[n]);
                QT[rr][i]     = lo_bf(qw[n]);
                QT[rr + 1][i] = hi_bf(qw[n]);
            }
        }
    }
    __syncthreads();

    const int it = t & 63, jb = t >> 6;
    float kk[16], qk[16];
#pragma unroll
    for (int m = 0; m < 16; ++m) { kk[m] = 0.f; qk[m] = 0.f; }
#pragma unroll 2
    for (int r = 0; r < 256; ++r) {
        float ki = KT[r][it];
        float qi = QT[r][it];
        float4 ka = *(const float4*)&KT[r][jb * 16 + 0];
        float4 kb = *(const float4*)&KT[r][jb * 16 + 4];
        float4 kc = *(const float4*)&KT[r][jb * 16 + 8];
        float4 kd = *(const float4*)&KT[r][jb * 16 + 12];
        float kj[16] = {ka.x, ka.y, ka.z, ka.w, kb.x, kb.y, kb.z, kb.w,
                        kc.x, kc.y, kc.z, kc.w, kd.x, kd.y, kd.z, kd.w};
#pragma unroll
        for (int m = 0; m < 16; ++m) { kk[m] += ki * kj[m]; qk[m] += qi * kj[m]; }
    }

    const float bta = beta[(size_t)(tb + it) * 4 + h];
    u16t* ag = Agb + (size_t)bhc * 4096 + (size_t)it * 64 + jb * 16;
#pragma unroll
    for (int m = 0; m < 16; ++m) {
        int j = jb * 16 + m;
        Af[it][j] = (j < it) ? bta * kk[m] : 0.f;
    }
#pragma unroll
    for (int m4 = 0; m4 < 4; ++m4) {
        ushort4 o;
        o.x = f2bf((jb * 16 + m4 * 4 + 0 <= it) ? qk[m4 * 4 + 0] : 0.f);
        o.y = f2bf((jb * 16 + m4 * 4 + 1 <= it) ? qk[m4 * 4 + 1] : 0.f);
        o.z = f2bf((jb * 16 + m4 * 4 + 2 <= it) ? qk[m4 * 4 + 2] : 0.f);
        o.w = f2bf((jb * 16 + m4 * 4 + 3 <= it) ? qk[m4 * 4 + 3] : 0.f);
        *(ushort4*)&ag[m4 * 4] = o;
    }
    __syncthreads();

    if (t < 64) {
        const int ccol = t;
        float tc[64];
#pragma unroll
        for (int j = 0; j < 64; ++j) tc[j] = (j == ccol) ? 1.f : 0.f;
#pragma unroll
        for (int i = 1; i < 64; ++i) {
            float a = 0.f;
#pragma unroll
            for (int j = 0; j < i; ++j) a += Af[i][j] * tc[j];
            tc[i] -= a;
        }
        u16t* th = Tghi + (size_t)bhc * 4096;
        u16t* tl = Tglo + (size_t)bhc * 4096;
#pragma unroll
        for (int i = 0; i < 64; ++i) {
            u16t hi = f2bf(tc[i]);
            th[i * 64 + ccol] = hi;
            tl[i * 64 + ccol] = f2bf(tc[i] - bf2f(hi));
        }
    }
}

// ====== MFMA scan (R10 best-known): XCD-affinity, 128 blocks, 4 waves ======
__global__ __launch_bounds__(256, 1) void scan_mfma(const u16t* __restrict__ qcb,
                                                    const u16t* __restrict__ kcb,
                                                    const u16t* __restrict__ ktr,
                                                    const u16t* __restrict__ vcb,
                                                    const float* __restrict__ beta,
                                                    const u16t* __restrict__ TghiG,
                                                    const u16t* __restrict__ TgloG,
                                                    const u16t* __restrict__ AgbG,
                                                    u16t* __restrict__ o_raw) {
    __shared__ u16t Shi[16 * 256];  // [v][r] slot-XOR swizzled
    __shared__ u16t Slo[16 * 256];
    __shared__ u16t Rhi[16 * 64];   // [v][t] slot-XOR swizzled
    __shared__ u16t Rlo[16 * 64];
    __shared__ u16t Uhi[16 * 64];
    __shared__ u16t Ulo[16 * 64];

    const int t = threadIdx.x, l = t & 63, w = t >> 6;
    const int bh = blockIdx.x & 7, vt = blockIdx.x >> 3;
    const int b = bh >> 2, h = bh & 3;
    const int vcol0 = vt * 16;
    const int vlow = l & 15, g4 = l >> 4;

    for (int i = t; i < 16 * 256; i += 256) { Shi[i] = 0; Slo[i] = 0; }
    f32x4 sf[4];
#pragma unroll
    for (int q = 0; q < 4; ++q) sf[q] = (f32x4){0.f, 0.f, 0.f, 0.f};

    bf16x8 kf[8], qf[8], tfh[2], tfl[2], af[2], kcf[8];
    u16t vfb[4];
    float bta[4];

    auto loadKQ = [&](int c) {
        const size_t rb = (size_t)(b * 2048 + c * 64 + 16 * w + vlow) * 1024 + h * 256 + g4 * 8;
#pragma unroll
        for (int ks = 0; ks < 8; ++ks) {
            kf[ks] = *(const bf16x8*)(kcb + rb + ks * 32);
            qf[ks] = *(const bf16x8*)(qcb + rb + ks * 32);
        }
    };
    auto loadVB = [&](int c) {
        const int r0 = b * 2048 + c * 64 + 16 * w + 4 * g4;
#pragma unroll
        for (int rg = 0; rg < 4; ++rg) {
            vfb[rg] = vcb[(size_t)(r0 + rg) * 1024 + h * 256 + vcol0 + vlow];
            bta[rg] = beta[(size_t)(r0 + rg) * 4 + h];
        }
    };
    auto loadT = [&](int c) {
        const size_t tb2 = (size_t)(bh * 32 + c) * 4096 + (size_t)(16 * w + vlow) * 64 + g4 * 8;
        tfh[0] = *(const bf16x8*)(TghiG + tb2);
        tfh[1] = *(const bf16x8*)(TghiG + tb2 + 32);
        tfl[0] = *(const bf16x8*)(TgloG + tb2);
        tfl[1] = *(const bf16x8*)(TgloG + tb2 + 32);
    };
    auto loadA = [&](int c) {
        const size_t tb2 = (size_t)(bh * 32 + c) * 4096 + (size_t)(16 * w + vlow) * 64 + g4 * 8;
        af[0] = *(const bf16x8*)(AgbG + tb2);
        af[1] = *(const bf16x8*)(AgbG + tb2 + 32);
    };
    auto loadKC = [&](int c) {
        const size_t cb2 = ((size_t)bh * 256 + 64 * w + vlow) * 2048 + c * 64 + g4 * 8;
#pragma unroll
        for (int q2 = 0; q2 < 4; ++q2) {
            kcf[q2 * 2 + 0] = *(const bf16x8*)(ktr + cb2 + (size_t)(16 * q2) * 2048);
            kcf[q2 * 2 + 1] = *(const bf16x8*)(ktr + cb2 + (size_t)(16 * q2) * 2048 + 32);
        }
    };

    loadKQ(0); loadVB(0); loadT(0); loadA(0); loadKC(0);
    __syncthreads();

    for (int c = 0; c < NCH; ++c) {
        const int cn = (c + 1 < NCH) ? c + 1 : c;
        const int trow0 = b * 2048 + c * 64;

        // ---- phase A: W = K*(Shi+Slo); O1 = Q*(Shi+Slo) ----
        f32x4 Wacc = (f32x4){0.f, 0.f, 0.f, 0.f};
        f32x4 O1   = (f32x4){0.f, 0.f, 0.f, 0.f};
#pragma unroll
        for (int ks = 0; ks < 8; ++ks) {
            const int pb = (((ks * 4 + g4) ^ (vlow & 7)) << 3);
            bf16x8 bH = *(const bf16x8*)&Shi[vlow * 256 + pb];
            bf16x8 bL = *(const bf16x8*)&Slo[vlow * 256 + pb];
            Wacc = MFMA(kf[ks], bH, Wacc); Wacc = MFMA(kf[ks], bL, Wacc);
            O1   = MFMA(qf[ks], bH, O1);   O1   = MFMA(qf[ks], bL, O1);
        }
        // R = beta*(V - W) -> LDS hi/lo
        {
            const int tslot = 2 * w + (g4 >> 1);
            const int base = vlow * 64 + ((tslot ^ (vlow & 7)) << 3) + ((g4 & 1) << 2);
            u16t rh[4], rl[4];
#pragma unroll
            for (int rg = 0; rg < 4; ++rg) {
                float rv = bta[rg] * (bf2f(vfb[rg]) - Wacc[rg]);
                rh[rg] = f2bf(rv);
                rl[rg] = f2bf(rv - bf2f(rh[rg]));
            }
            uint2 ph, pl;
            ph.x = (u32t)rh[0] | ((u32t)rh[1] << 16); ph.y = (u32t)rh[2] | ((u32t)rh[3] << 16);
            pl.x = (u32t)rl[0] | ((u32t)rl[1] << 16); pl.y = (u32t)rl[2] | ((u32t)rl[3] << 16);
            *(uint2*)&Rhi[base] = ph;
            *(uint2*)&Rlo[base] = pl;
        }
        loadKQ(cn);
        loadVB(cn);
        __syncthreads();

        // ---- phase B: U = (Thi+Tlo)*(Rhi+Rlo) ----
        f32x4 Uacc = (f32x4){0.f, 0.f, 0.f, 0.f};
#pragma unroll
        for (int ks = 0; ks < 2; ++ks) {
            const int pb = (((ks * 4 + g4) ^ (vlow & 7)) << 3);
            bf16x8 bH = *(const bf16x8*)&Rhi[vlow * 64 + pb];
            bf16x8 bL = *(const bf16x8*)&Rlo[vlow * 64 + pb];
            Uacc = MFMA(tfh[ks], bH, Uacc);
            Uacc = MFMA(tfh[ks], bL, Uacc);
            Uacc = MFMA(tfl[ks], bH, Uacc);
        }
        {
            const int tslot = 2 * w + (g4 >> 1);
            const int base = vlow * 64 + ((tslot ^ (vlow & 7)) << 3) + ((g4 & 1) << 2);
            u16t uh[4], ul[4];
#pragma unroll
            for (int rg = 0; rg < 4; ++rg) {
                uh[rg] = f2bf(Uacc[rg]);
                ul[rg] = f2bf(Uacc[rg] - bf2f(uh[rg]));
            }
            uint2 ph, pl;
            ph.x = (u32t)uh[0] | ((u32t)uh[1] << 16); ph.y = (u32t)uh[2] | ((u32t)uh[3] << 16);
            pl.x = (u32t)ul[0] | ((u32t)ul[1] << 16); pl.y = (u32t)ul[2] | ((u32t)ul[3] << 16);
            *(uint2*)&Uhi[base] = ph;
            *(uint2*)&Ulo[base] = pl;
        }
        loadT(cn);
        __syncthreads();

        // ---- phase C: O = O1 + A*U ; S += K^T*U ; refresh S mirror ----
        bf16x8 uhf[2], ulf[2];
#pragma unroll
        for (int ks = 0; ks < 2; ++ks) {
            const int pb = (((ks * 4 + g4) ^ (vlow & 7)) << 3);
            uhf[ks] = *(const bf16x8*)&Uhi[vlow * 64 + pb];
            ulf[ks] = *(const bf16x8*)&Ulo[vlow * 64 + pb];
        }
        f32x4 Oacc = O1;
#pragma unroll
        for (int ks = 0; ks < 2; ++ks) {
            Oacc = MFMA(af[ks], uhf[ks], Oacc);
            Oacc = MFMA(af[ks], ulf[ks], Oacc);
        }
#pragma unroll
        for (int rg = 0; rg < 4; ++rg)
            o_raw[(size_t)(trow0 + 16 * w + 4 * g4 + rg) * 1024 + h * 256 + vcol0 + vlow] = f2bf(Oacc[rg]);
        loadA(cn);

#pragma unroll
        for (int q = 0; q < 4; ++q) {
#pragma unroll
            for (int ks = 0; ks < 2; ++ks) {
                sf[q] = MFMA(kcf[q * 2 + ks], uhf[ks], sf[q]);
                sf[q] = MFMA(kcf[q * 2 + ks], ulf[ks], sf[q]);
            }
        }
        loadKC(cn);

        // S mirror refresh (hi/lo)
#pragma unroll
        for (int q = 0; q < 4; ++q) {
            u16t sh[4], sl[4];
#pragma unroll
            for (int rg = 0; rg < 4; ++rg) {
                u16t hi = f2bf(sf[q][rg]);
                sh[rg] = hi;
                sl[rg] = f2bf(sf[q][rg] - bf2f(hi));
            }
            const int rslot = 8 * w + 2 * q + (g4 >> 1);
            const int base = vlow * 256 + ((rslot ^ (vlow & 7)) << 3) + ((g4 & 1) << 2);
            uint2 ph, pl;
            ph.x = (u32t)sh[0] | ((u32t)sh[1] << 16); ph.y = (u32t)sh[2] | ((u32t)sh[3] << 16);
            pl.x = (u32t)sl[0] | ((u32t)sl[1] << 16); pl.y = (u32t)sl[2] | ((u32t)sl[3] << 16);
            *(uint2*)&Shi[base] = ph;
            *(uint2*)&Slo[base] = pl;
        }
        __syncthreads();
    }
}

// =================== rms_norm (bf16 in -> bf16 out) ======================
__global__ __launch_bounds__(256) void rms_kernel(const u16t* __restrict__ in,
                                                  const float* __restrict__ w,
                                                  u16t* __restrict__ out) {
    const int gw   = (blockIdx.x * blockDim.x + threadIdx.x) >> 6;
    const int lane = threadIdx.x & 63;
    const int r = gw >> 2;
    const int h = gw & 3;
    const size_t base = (size_t)r * HIDD + h * 256 + lane * 4;
    ushort4 xv = *(const ushort4*)&in[base];
    float x0 = bf2f(xv.x), x1 = bf2f(xv.y), x2 = bf2f(xv.z), x3 = bf2f(xv.w);
    float ss = x0 * x0 + x1 * x1 + x2 * x2 + x3 * x3;
    ss = waveReduceSum(ss);
    const float sc = rsqrtf(ss * (1.0f / 256.0f) + 1e-5f);
    float4 wv = *(const float4*)&w[lane * 4];
    ushort4 o;
    o.x = f2bf(x0 * sc * wv.x); o.y = f2bf(x1 * sc * wv.y);
    o.z = f2bf(x2 * sc * wv.z); o.w = f2bf(x3 * sc * wv.w);
    *(ushort4*)&out[base] = o;
}

extern "C" void kernel_launch(void* const* d_in, const int* in_sizes, int n_in,
                              void* d_out, int out_size, void* d_ws, size_t ws_size,
                              hipStream_t stream) {
    const float* X      = (const float*)d_in[0];
    const float* Wq     = (const float*)d_in[1];
    const float* Wk     = (const float*)d_in[2];
    const float* Wv     = (const float*)d_in[3];
    const float* Wb     = (const float*)d_in[4];
    const float* conv_q = (const float*)d_in[5];
    const float* conv_k = (const float*)d_in[6];
    const float* conv_v = (const float*)d_in[7];
    const float* norm_w = (const float*)d_in[8];
    const float* Wo     = (const float*)d_in[9];
    float* out = (float*)d_out;

    char* W8 = (char*)d_ws;
    const size_t MB = 1u << 20;
    u16t* Xbf   = (u16t*)(W8 + 0 * MB);
    u16t* o_raw = Xbf;
    u16t* qpre  = (u16t*)(W8 + 8 * MB);
    u16t* o_nrm = qpre;
    u16t* kpre  = (u16t*)(W8 + 16 * MB);
    u16t* Tghi  = (u16t*)(W8 + 16 * MB);
    u16t* Tglo  = (u16t*)(W8 + 18 * MB);
    u16t* Agb   = (u16t*)(W8 + 20 * MB);
    u16t* vpre  = (u16t*)(W8 + 24 * MB);
    u16t* ktr   = (u16t*)(W8 + 24 * MB);
    u16t* WqT   = (u16t*)(W8 + 32 * MB);
    u16t* qcb   = (u16t*)(W8 + 32 * MB);
    u16t* WkT   = (u16t*)(W8 + 40 * MB);
    u16t* kcb   = (u16t*)(W8 + 40 * MB);
    u16t* WvT   = (u16t*)(W8 + 48 * MB);
    u16t* vcb   = (u16t*)(W8 + 48 * MB);
    u16t* WoT   = (u16t*)(W8 + 56 * MB);
    float* betab = (float*)(W8 + 58 * MB);

    const size_t PL = 4194304;   // 8 MB plane stride in u16 elements

    // fused: W transposes (z 0..3) + X f32->bf16 (z 4..11)
    pre_kernel<<<dim3(16, 16, 12), 256, 0, stream>>>(X, Xbf, Wq, Wk, Wv, Wo,
                                                     WqT, WkT, WvT, WoT);

    // fused QKV projection; XCD swizzle CX=2
    gemm_mfma<<<dim3(24, 32), 256, 0, stream>>>(Xbf, WqT, nullptr, qpre, 1,
                                                ROWS, 3072, HIDD, PL, PL, 2);

    // conv q (y=0), conv v (y=1), beta (y=2, x<1024)
    conv_qvb<<<dim3(ROWS, 3), 256, 0, stream>>>(qpre, conv_q, qcb, vpre, conv_v, vcb,
                                                X, Wb, betab);
    conv_k_chunk<<<256, 256, 0, stream>>>(kpre, conv_k, kcb, ktr);

    prep_kernel<<<256, 256, 0, stream>>>(qcb, kcb, betab, Tghi, Tglo, Agb);
    scan_mfma<<<128, 256, 0, stream>>>(qcb, kcb, ktr, vcb, betab, Tghi, Tglo, Agb, o_raw);

    rms_kernel<<<ROWS, 256, 0, stream>>>(o_raw, norm_w, o_nrm);
    gemm_mfma<<<dim3(8, 32), 256, 0, stream>>>(o_nrm, WoT, out, nullptr, 0,
                                               ROWS, HIDD, HIDD, 0, 0, 1);
}